// Round 20
// baseline (343.214 us; speedup 1.0000x reference)
//
#include <hip/hip_runtime.h>

#define N_NODES 10000
#define N_EDGES 320000
#define N_CAND  100000
#define HID     256
#define N_MP    3
#define N_ATYPE 100

typedef short bf16x8 __attribute__((ext_vector_type(8)));
typedef float f32x4  __attribute__((ext_vector_type(4)));

static __device__ __forceinline__ float relu_f(float x) { return x > 0.f ? x : 0.f; }

// split fp32 -> bf16 hi (truncate) + bf16 lo (RNE of residual)
static __device__ __forceinline__ void split_bf16(float s, unsigned short& hi,
                                                  unsigned short& lo)
{
    unsigned u = __float_as_uint(s);
    hi = (unsigned short)(u >> 16);
    float rem = s - __uint_as_float(u & 0xffff0000u);
    unsigned v = __float_as_uint(rem);
    unsigned r = v + 0x7fffu + ((v >> 16) & 1u);
    lo = (unsigned short)(r >> 16);
}

// LDS 16B-block swizzle: consistent on write and read (verified R19)
static __device__ __forceinline__ int swz_blk(int rloc, int blk)
{
    return blk ^ (rloc & 7) ^ ((rloc & 3) << 3);
}

// ---------------------------------------------------------------------------
// bf16x3 MFMA 32x32 tile (verified R10-R19: absmax 3.8e-6).
// ---------------------------------------------------------------------------
static __device__ __forceinline__ void mfma_tile(
    const unsigned short* __restrict__ Ah, const unsigned short* __restrict__ Al,
    const unsigned short* __restrict__ Wh, const unsigned short* __restrict__ Wl,
    const float* __restrict__ bias, const float* __restrict__ scale,
    float* __restrict__ outF, int M, int mb, int nb, int doRelu)
{
    int l  = threadIdx.x & 63;
    int li = l & 15;
    int g  = l >> 4;

    int r0 = mb + li;       if (r0 >= M) r0 = M - 1;
    int r1 = mb + 16 + li;  if (r1 >= M) r1 = M - 1;
    int c0 = nb + li;
    int c1 = nb + 16 + li;

    const unsigned short* pA0h = Ah + (size_t)r0 * 256 + g * 8;
    const unsigned short* pA1h = Ah + (size_t)r1 * 256 + g * 8;
    const unsigned short* pA0l = Al + (size_t)r0 * 256 + g * 8;
    const unsigned short* pA1l = Al + (size_t)r1 * 256 + g * 8;
    const unsigned short* pB0h = Wh + (size_t)c0 * 256 + g * 8;
    const unsigned short* pB1h = Wh + (size_t)c1 * 256 + g * 8;
    const unsigned short* pB0l = Wl + (size_t)c0 * 256 + g * 8;
    const unsigned short* pB1l = Wl + (size_t)c1 * 256 + g * 8;

    f32x4 acc00 = {0.f, 0.f, 0.f, 0.f};
    f32x4 acc01 = {0.f, 0.f, 0.f, 0.f};
    f32x4 acc10 = {0.f, 0.f, 0.f, 0.f};
    f32x4 acc11 = {0.f, 0.f, 0.f, 0.f};

    #pragma unroll
    for (int ks = 0; ks < 8; ++ks) {
        int o = ks * 32;
        bf16x8 a0h = *(const bf16x8*)(pA0h + o);
        bf16x8 a1h = *(const bf16x8*)(pA1h + o);
        bf16x8 a0l = *(const bf16x8*)(pA0l + o);
        bf16x8 a1l = *(const bf16x8*)(pA1l + o);
        bf16x8 b0h = *(const bf16x8*)(pB0h + o);
        bf16x8 b1h = *(const bf16x8*)(pB1h + o);
        bf16x8 b0l = *(const bf16x8*)(pB0l + o);
        bf16x8 b1l = *(const bf16x8*)(pB1l + o);

        acc00 = __builtin_amdgcn_mfma_f32_16x16x32_bf16(a0h, b0h, acc00, 0, 0, 0);
        acc01 = __builtin_amdgcn_mfma_f32_16x16x32_bf16(a0h, b1h, acc01, 0, 0, 0);
        acc10 = __builtin_amdgcn_mfma_f32_16x16x32_bf16(a1h, b0h, acc10, 0, 0, 0);
        acc11 = __builtin_amdgcn_mfma_f32_16x16x32_bf16(a1h, b1h, acc11, 0, 0, 0);

        acc00 = __builtin_amdgcn_mfma_f32_16x16x32_bf16(a0h, b0l, acc00, 0, 0, 0);
        acc01 = __builtin_amdgcn_mfma_f32_16x16x32_bf16(a0h, b1l, acc01, 0, 0, 0);
        acc10 = __builtin_amdgcn_mfma_f32_16x16x32_bf16(a1h, b0l, acc10, 0, 0, 0);
        acc11 = __builtin_amdgcn_mfma_f32_16x16x32_bf16(a1h, b1l, acc11, 0, 0, 0);

        acc00 = __builtin_amdgcn_mfma_f32_16x16x32_bf16(a0l, b0h, acc00, 0, 0, 0);
        acc01 = __builtin_amdgcn_mfma_f32_16x16x32_bf16(a0l, b1h, acc01, 0, 0, 0);
        acc10 = __builtin_amdgcn_mfma_f32_16x16x32_bf16(a1l, b0h, acc10, 0, 0, 0);
        acc11 = __builtin_amdgcn_mfma_f32_16x16x32_bf16(a1l, b1h, acc11, 0, 0, 0);
    }

    #pragma unroll
    for (int rt = 0; rt < 2; ++rt) {
        #pragma unroll
        for (int ct = 0; ct < 2; ++ct) {
            f32x4 a = rt ? (ct ? acc11 : acc10) : (ct ? acc01 : acc00);
            int col = nb + ct * 16 + li;
            float bv = bias ? bias[col] : 0.f;
            #pragma unroll
            for (int j = 0; j < 4; ++j) {
                int row = mb + rt * 16 + g * 4 + j;
                if (row >= M) continue;
                float v = a[j] + bv;
                if (doRelu) v = relu_f(v);
                if (scale) v *= scale[row];
                outF[(size_t)row * 256 + col] = v;
            }
        }
    }
}

// ---------------------------------------------------------------------------
// E0 tile via direct fp32 operands (in-register split). [verified R17]
// ---------------------------------------------------------------------------
static __device__ __forceinline__ void mfma_tile_e0(
    const float* __restrict__ A, const float* __restrict__ B,
    const float* __restrict__ bias, float* __restrict__ C,
    int M, int mb, int nb)
{
    int l  = threadIdx.x & 63;
    int li = l & 15;
    int g  = l >> 4;

    int r0 = mb + li;       if (r0 >= M) r0 = M - 1;
    int r1 = mb + 16 + li;  if (r1 >= M) r1 = M - 1;
    int c0 = nb + li;
    int c1 = nb + 16 + li;

    f32x4 acc00 = {0.f, 0.f, 0.f, 0.f};
    f32x4 acc01 = {0.f, 0.f, 0.f, 0.f};
    f32x4 acc10 = {0.f, 0.f, 0.f, 0.f};
    f32x4 acc11 = {0.f, 0.f, 0.f, 0.f};

    #pragma unroll
    for (int ks = 0; ks < 8; ++ks) {
        int k0 = ks * 32 + g * 8;
        float av0[8], av1[8];
        {
            float4 x0 = *(const float4*)(A + (size_t)r0 * 256 + k0);
            float4 x1 = *(const float4*)(A + (size_t)r0 * 256 + k0 + 4);
            av0[0]=x0.x; av0[1]=x0.y; av0[2]=x0.z; av0[3]=x0.w;
            av0[4]=x1.x; av0[5]=x1.y; av0[6]=x1.z; av0[7]=x1.w;
            float4 y0 = *(const float4*)(A + (size_t)r1 * 256 + k0);
            float4 y1 = *(const float4*)(A + (size_t)r1 * 256 + k0 + 4);
            av1[0]=y0.x; av1[1]=y0.y; av1[2]=y0.z; av1[3]=y0.w;
            av1[4]=y1.x; av1[5]=y1.y; av1[6]=y1.z; av1[7]=y1.w;
        }
        float bv0[8], bv1[8];
        #pragma unroll
        for (int j = 0; j < 8; ++j) {
            bv0[j] = B[(size_t)(k0 + j) * 256 + c0];
            bv1[j] = B[(size_t)(k0 + j) * 256 + c1];
        }
        bf16x8 a0h, a0l, a1h, a1l, b0h, b0l, b1h, b1l;
        #pragma unroll
        for (int j = 0; j < 8; ++j) {
            unsigned short h, lo;
            split_bf16(av0[j], h, lo); a0h[j] = (short)h; a0l[j] = (short)lo;
            split_bf16(av1[j], h, lo); a1h[j] = (short)h; a1l[j] = (short)lo;
            split_bf16(bv0[j], h, lo); b0h[j] = (short)h; b0l[j] = (short)lo;
            split_bf16(bv1[j], h, lo); b1h[j] = (short)h; b1l[j] = (short)lo;
        }

        acc00 = __builtin_amdgcn_mfma_f32_16x16x32_bf16(a0h, b0h, acc00, 0, 0, 0);
        acc01 = __builtin_amdgcn_mfma_f32_16x16x32_bf16(a0h, b1h, acc01, 0, 0, 0);
        acc10 = __builtin_amdgcn_mfma_f32_16x16x32_bf16(a1h, b0h, acc10, 0, 0, 0);
        acc11 = __builtin_amdgcn_mfma_f32_16x16x32_bf16(a1h, b1h, acc11, 0, 0, 0);

        acc00 = __builtin_amdgcn_mfma_f32_16x16x32_bf16(a0h, b0l, acc00, 0, 0, 0);
        acc01 = __builtin_amdgcn_mfma_f32_16x16x32_bf16(a0h, b1l, acc01, 0, 0, 0);
        acc10 = __builtin_amdgcn_mfma_f32_16x16x32_bf16(a1h, b0l, acc10, 0, 0, 0);
        acc11 = __builtin_amdgcn_mfma_f32_16x16x32_bf16(a1h, b1l, acc11, 0, 0, 0);

        acc00 = __builtin_amdgcn_mfma_f32_16x16x32_bf16(a0l, b0h, acc00, 0, 0, 0);
        acc01 = __builtin_amdgcn_mfma_f32_16x16x32_bf16(a0l, b1h, acc01, 0, 0, 0);
        acc10 = __builtin_amdgcn_mfma_f32_16x16x32_bf16(a1l, b0h, acc10, 0, 0, 0);
        acc11 = __builtin_amdgcn_mfma_f32_16x16x32_bf16(a1l, b1h, acc11, 0, 0, 0);
    }

    #pragma unroll
    for (int rt = 0; rt < 2; ++rt) {
        #pragma unroll
        for (int ct = 0; ct < 2; ++ct) {
            f32x4 a = rt ? (ct ? acc11 : acc10) : (ct ? acc01 : acc00);
            int col = nb + ct * 16 + li;
            float bv = bias[col];
            #pragma unroll
            for (int j = 0; j < 4; ++j) {
                int row = mb + rt * 16 + g * 4 + j;
                if (row >= M) continue;
                C[(size_t)row * 256 + col] = a[j] + bv;
            }
        }
    }
}

// ---------------------------------------------------------------------------
// k_prep: LDS-transpose weight split (blocks 0..79) + E0 MFMA (blocks 80..87)
// + degree histogram (all blocks, strided). Grid: 1280 x 256. [verified R19]
// ---------------------------------------------------------------------------
__global__ __launch_bounds__(256) void k_prep(
    const float* __restrict__ conv_W, const float* __restrict__ s_W1,
    const float* __restrict__ atom_embed, const float* __restrict__ atom_W,
    const float* __restrict__ atom_b, const int* __restrict__ ei,
    unsigned short* __restrict__ WTh, unsigned short* __restrict__ WTl,
    float* __restrict__ E0, int* __restrict__ dout, int* __restrict__ din)
{
    int bid = blockIdx.x;
    if (bid < 80) {
        __shared__ float T[64][65];
        int mat = bid >> 4;
        int t   = bid & 15;
        int ti  = t >> 2;
        int tj  = t & 3;
        const float* src = (mat < 3) ? conv_W + (size_t)mat * 65536
                                     : s_W1 + (size_t)(mat - 3) * 65536;
        #pragma unroll
        for (int i = 0; i < 16; ++i) {
            int flat = i * 256 + threadIdx.x;
            int kr = flat >> 6;
            int nc = flat & 63;
            T[kr][nc] = src[(size_t)(ti * 64 + kr) * 256 + tj * 64 + nc];
        }
        __syncthreads();
        #pragma unroll
        for (int i = 0; i < 16; ++i) {
            int flat = i * 256 + threadIdx.x;
            int nr = flat >> 6;
            int kc = flat & 63;
            unsigned short hi, lo;
            split_bf16(T[kc][nr], hi, lo);
            size_t oi = (size_t)mat * 65536 +
                        (size_t)(tj * 64 + nr) * 256 + ti * 64 + kc;
            WTh[oi] = hi;
            WTl[oi] = lo;
        }
    } else if (bid < 88) {
        int w = (bid - 80) * 4 + (threadIdx.x >> 6);
        if (w < 32) {
            int x = w >> 3, y = w & 7;
            mfma_tile_e0(atom_embed, atom_W, atom_b, E0, N_ATYPE, x * 32, y * 32);
        }
    }
    int gidx = bid * 256 + threadIdx.x;
    if (gidx < N_EDGES) {
        atomicAdd(&dout[ei[gidx]], 1);
        atomicAdd(&din[ei[N_EDGES + gidx]], 1);
    }
}

// ---------------------------------------------------------------------------
// k_nhs: norm + h0 (blocks 0..2499) + degi exclusive scan (block 2500).
// ---------------------------------------------------------------------------
__global__ __launch_bounds__(256) void k_nhs(
    const int* __restrict__ types, const float* __restrict__ E0,
    const int* __restrict__ dout, const int* __restrict__ din,
    float* __restrict__ ns, float* __restrict__ nd, float* __restrict__ h,
    int* __restrict__ off)
{
    if (blockIdx.x == 2500) {
        __shared__ int part[256];
        int t = threadIdx.x;
        const int chunk = 40;
        int base = t * chunk;
        int s = 0;
        for (int i = 0; i < chunk; ++i) {
            int idx = base + i;
            if (idx < N_NODES) s += din[idx];
        }
        part[t] = s;
        __syncthreads();
        for (int d = 1; d < 256; d <<= 1) {
            int v = (t >= d) ? part[t - d] : 0;
            __syncthreads();
            part[t] += v;
            __syncthreads();
        }
        int run = (t == 0) ? 0 : part[t - 1];
        if (t == 0) off[0] = 0;
        for (int i = 0; i < chunk; ++i) {
            int idx = base + i;
            if (idx < N_NODES) { run += din[idx]; off[idx + 1] = run; }
        }
        return;
    }
    int node = blockIdx.x * 4 + (threadIdx.x >> 6);
    int lane = threadIdx.x & 63;
    if (node >= N_NODES) return;
    int o  = dout[node];
    int in = din[node];
    float nsv = (o  > 0) ? (1.0f / sqrtf((float)o))  : 0.f;
    float ndv = (in > 0) ? (1.0f / sqrtf((float)in)) : 0.f;
    if (lane == 0) { ns[node] = nsv; nd[node] = ndv; }
    int t = types[node];
    float4 v = ((const float4*)E0)[(size_t)t * 64 + lane];
    v.x *= nsv; v.y *= nsv; v.z *= nsv; v.w *= nsv;
    ((float4*)h)[(size_t)node * 64 + lane] = v;
}

__global__ void k_fill(const int* __restrict__ ei, const int* __restrict__ off,
                       int* __restrict__ cur, int* __restrict__ csr)
{
    int e = blockIdx.x * blockDim.x + threadIdx.x;
    if (e >= N_EDGES) return;
    int d = ei[N_EDGES + e];
    int p = off[d] + atomicAdd(&cur[d], 1);
    csr[p] = ei[e];
}

// ---------------------------------------------------------------------------
// Persistent column-chunked aggregation. [verified R10/R14]
// ---------------------------------------------------------------------------
__global__ __launch_bounds__(256) void k_agg(
    const float* __restrict__ h, const float* __restrict__ nd,
    const int* __restrict__ off, const int* __restrict__ csr,
    unsigned short* __restrict__ Ah, unsigned short* __restrict__ Al)
{
    int bid  = blockIdx.x;
    int slot = bid & 7;
    int c    = slot >> 1;
    int p    = ((bid >> 3) << 1) | (slot & 1);
    int wave = threadIdx.x >> 6;
    int lane = threadIdx.x & 63;
    int wi   = p * 4 + wave;
    int col  = c * 64 + lane;

    for (int node = wi; node < N_NODES; node += 2048) {
        int s0 = off[node], s1 = off[node + 1];
        float a0 = 0.f, a1 = 0.f, a2 = 0.f, a3 = 0.f;
        float a4 = 0.f, a5 = 0.f, a6 = 0.f, a7 = 0.f;
        int e = s0;
        for (; e + 8 <= s1; e += 8) {
            int i0 = csr[e],     i1 = csr[e + 1], i2 = csr[e + 2], i3 = csr[e + 3];
            int i4 = csr[e + 4], i5 = csr[e + 5], i6 = csr[e + 6], i7 = csr[e + 7];
            float v0 = h[(size_t)i0 * 256 + col];
            float v1 = h[(size_t)i1 * 256 + col];
            float v2 = h[(size_t)i2 * 256 + col];
            float v3 = h[(size_t)i3 * 256 + col];
            float v4 = h[(size_t)i4 * 256 + col];
            float v5 = h[(size_t)i5 * 256 + col];
            float v6 = h[(size_t)i6 * 256 + col];
            float v7 = h[(size_t)i7 * 256 + col];
            a0 += v0; a1 += v1; a2 += v2; a3 += v3;
            a4 += v4; a5 += v5; a6 += v6; a7 += v7;
        }
        for (; e < s1; ++e)
            a0 += h[(size_t)csr[e] * 256 + col];
        float s = (((a0 + a1) + (a2 + a3)) + ((a4 + a5) + (a6 + a7))) * nd[node];
        unsigned short hi, lo;
        split_bf16(s, hi, lo);
        Ah[(size_t)node * 256 + col] = hi;
        Al[(size_t)node * 256 + col] = lo;
    }
}

// conv GEMM (layers 0,1): fp32 out, relu, ns scale. 628 blocks x 256 thr.
__global__ __launch_bounds__(256) void k_conv(
    const unsigned short* __restrict__ Ah, const unsigned short* __restrict__ Al,
    const unsigned short* __restrict__ Wh, const unsigned short* __restrict__ Wl,
    const float* __restrict__ bias, const float* __restrict__ scale,
    float* __restrict__ outF, int M)
{
    int t = blockIdx.x * 4 + (threadIdx.x >> 6);
    int x = t >> 3, y = t & 7;
    if (x * 32 >= M) return;
    mfma_tile(Ah, Al, Wh, Wl, bias, scale, outF, M, x * 32, y * 32, 1);
}

// ---------------------------------------------------------------------------
// k_convpq v2: fused conv layer 2 + HALF of the P/Q projection per block.
// Grid: 626 x 512. Block b: panel = b>>1 (32 rows), sel = b&1 (0->P, 1->Q).
// Phase 1 (duplicated across the P/Q block pair — MFMA pipe is idle anyway):
//   8 waves compute the conv panel -> swizzled split-bf16 in LDS.
// Phase 2: ONE tile per wave (y = wave). 2x blocks vs R19 -> 2x occupancy.
// ---------------------------------------------------------------------------
__global__ __launch_bounds__(512) void k_convpq(
    const unsigned short* __restrict__ Ah, const unsigned short* __restrict__ Al,
    const unsigned short* __restrict__ Wch, const unsigned short* __restrict__ Wcl,
    const float* __restrict__ bias,
    const unsigned short* __restrict__ WTh, const unsigned short* __restrict__ WTl,
    float* __restrict__ P, float* __restrict__ Q, int M)
{
    __shared__ unsigned short Lh[32 * 256];
    __shared__ unsigned short Ll[32 * 256];

    int w   = threadIdx.x >> 6;
    int l   = threadIdx.x & 63;
    int li  = l & 15;
    int g   = l >> 4;
    int mb  = (blockIdx.x >> 1) * 32;
    int sel = blockIdx.x & 1;

    if (mb + 32 > M) {
        for (int f = threadIdx.x; f < 32 * 256; f += 512) {
            int r = f >> 8;
            if (mb + r >= M) { Lh[f] = 0; Ll[f] = 0; }
        }
    }

    // ---- phase 1: conv tile (mb, nb = w*32) -> LDS ----
    {
        int nb = w * 32;
        int r0 = mb + li;       if (r0 >= M) r0 = M - 1;
        int r1 = mb + 16 + li;  if (r1 >= M) r1 = M - 1;
        int c0 = nb + li;
        int c1 = nb + 16 + li;

        const unsigned short* pA0h = Ah + (size_t)r0 * 256 + g * 8;
        const unsigned short* pA1h = Ah + (size_t)r1 * 256 + g * 8;
        const unsigned short* pA0l = Al + (size_t)r0 * 256 + g * 8;
        const unsigned short* pA1l = Al + (size_t)r1 * 256 + g * 8;
        const unsigned short* pB0h = Wch + (size_t)c0 * 256 + g * 8;
        const unsigned short* pB1h = Wch + (size_t)c1 * 256 + g * 8;
        const unsigned short* pB0l = Wcl + (size_t)c0 * 256 + g * 8;
        const unsigned short* pB1l = Wcl + (size_t)c1 * 256 + g * 8;

        f32x4 acc00 = {0.f, 0.f, 0.f, 0.f};
        f32x4 acc01 = {0.f, 0.f, 0.f, 0.f};
        f32x4 acc10 = {0.f, 0.f, 0.f, 0.f};
        f32x4 acc11 = {0.f, 0.f, 0.f, 0.f};

        #pragma unroll
        for (int ks = 0; ks < 8; ++ks) {
            int o = ks * 32;
            bf16x8 a0h = *(const bf16x8*)(pA0h + o);
            bf16x8 a1h = *(const bf16x8*)(pA1h + o);
            bf16x8 a0l = *(const bf16x8*)(pA0l + o);
            bf16x8 a1l = *(const bf16x8*)(pA1l + o);
            bf16x8 b0h = *(const bf16x8*)(pB0h + o);
            bf16x8 b1h = *(const bf16x8*)(pB1h + o);
            bf16x8 b0l = *(const bf16x8*)(pB0l + o);
            bf16x8 b1l = *(const bf16x8*)(pB1l + o);

            acc00 = __builtin_amdgcn_mfma_f32_16x16x32_bf16(a0h, b0h, acc00, 0, 0, 0);
            acc01 = __builtin_amdgcn_mfma_f32_16x16x32_bf16(a0h, b1h, acc01, 0, 0, 0);
            acc10 = __builtin_amdgcn_mfma_f32_16x16x32_bf16(a1h, b0h, acc10, 0, 0, 0);
            acc11 = __builtin_amdgcn_mfma_f32_16x16x32_bf16(a1h, b1h, acc11, 0, 0, 0);

            acc00 = __builtin_amdgcn_mfma_f32_16x16x32_bf16(a0h, b0l, acc00, 0, 0, 0);
            acc01 = __builtin_amdgcn_mfma_f32_16x16x32_bf16(a0h, b1l, acc01, 0, 0, 0);
            acc10 = __builtin_amdgcn_mfma_f32_16x16x32_bf16(a1h, b0l, acc10, 0, 0, 0);
            acc11 = __builtin_amdgcn_mfma_f32_16x16x32_bf16(a1h, b1l, acc11, 0, 0, 0);

            acc00 = __builtin_amdgcn_mfma_f32_16x16x32_bf16(a0l, b0h, acc00, 0, 0, 0);
            acc01 = __builtin_amdgcn_mfma_f32_16x16x32_bf16(a0l, b1h, acc01, 0, 0, 0);
            acc10 = __builtin_amdgcn_mfma_f32_16x16x32_bf16(a1l, b0h, acc10, 0, 0, 0);
            acc11 = __builtin_amdgcn_mfma_f32_16x16x32_bf16(a1l, b1h, acc11, 0, 0, 0);
        }

        #pragma unroll
        for (int rt = 0; rt < 2; ++rt) {
            #pragma unroll
            for (int ct = 0; ct < 2; ++ct) {
                f32x4 a = rt ? (ct ? acc11 : acc10) : (ct ? acc01 : acc00);
                int col = nb + ct * 16 + li;
                float bv = bias[col];
                #pragma unroll
                for (int j = 0; j < 4; ++j) {
                    int rloc = rt * 16 + g * 4 + j;
                    if (mb + rloc >= M) continue;
                    float v = relu_f(a[j] + bv);
                    unsigned short hi, lo;
                    split_bf16(v, hi, lo);
                    int blk2 = swz_blk(rloc, col >> 3);
                    int addr = rloc * 256 + blk2 * 8 + (col & 7);
                    Lh[addr] = hi;
                    Ll[addr] = lo;
                }
            }
        }
    }
    __syncthreads();

    // ---- phase 2: one tile per wave (half 'sel', column tile y = w) ----
    {
        const unsigned short* Bh = WTh + (size_t)(3 + sel) * 65536;
        const unsigned short* Bl = WTl + (size_t)(3 + sel) * 65536;
        float* C = sel ? Q : P;
        int nb = w * 32;
        int c0 = nb + li;
        int c1 = nb + 16 + li;

        f32x4 acc00 = {0.f, 0.f, 0.f, 0.f};
        f32x4 acc01 = {0.f, 0.f, 0.f, 0.f};
        f32x4 acc10 = {0.f, 0.f, 0.f, 0.f};
        f32x4 acc11 = {0.f, 0.f, 0.f, 0.f};

        #pragma unroll
        for (int ks = 0; ks < 8; ++ks) {
            int blk = ks * 4 + g;
            int b0 = swz_blk(li, blk);
            bf16x8 a0h = *(const bf16x8*)(&Lh[li * 256 + b0 * 8]);
            bf16x8 a0l = *(const bf16x8*)(&Ll[li * 256 + b0 * 8]);
            bf16x8 a1h = *(const bf16x8*)(&Lh[(16 + li) * 256 + b0 * 8]);
            bf16x8 a1l = *(const bf16x8*)(&Ll[(16 + li) * 256 + b0 * 8]);

            int o = ks * 32 + g * 8;
            bf16x8 b0h = *(const bf16x8*)(Bh + (size_t)c0 * 256 + o);
            bf16x8 b1h = *(const bf16x8*)(Bh + (size_t)c1 * 256 + o);
            bf16x8 b0l = *(const bf16x8*)(Bl + (size_t)c0 * 256 + o);
            bf16x8 b1l = *(const bf16x8*)(Bl + (size_t)c1 * 256 + o);

            acc00 = __builtin_amdgcn_mfma_f32_16x16x32_bf16(a0h, b0h, acc00, 0, 0, 0);
            acc01 = __builtin_amdgcn_mfma_f32_16x16x32_bf16(a0h, b1h, acc01, 0, 0, 0);
            acc10 = __builtin_amdgcn_mfma_f32_16x16x32_bf16(a1h, b0h, acc10, 0, 0, 0);
            acc11 = __builtin_amdgcn_mfma_f32_16x16x32_bf16(a1h, b1h, acc11, 0, 0, 0);

            acc00 = __builtin_amdgcn_mfma_f32_16x16x32_bf16(a0h, b0l, acc00, 0, 0, 0);
            acc01 = __builtin_amdgcn_mfma_f32_16x16x32_bf16(a0h, b1l, acc01, 0, 0, 0);
            acc10 = __builtin_amdgcn_mfma_f32_16x16x32_bf16(a1h, b0l, acc10, 0, 0, 0);
            acc11 = __builtin_amdgcn_mfma_f32_16x16x32_bf16(a1h, b1l, acc11, 0, 0, 0);

            acc00 = __builtin_amdgcn_mfma_f32_16x16x32_bf16(a0l, b0h, acc00, 0, 0, 0);
            acc01 = __builtin_amdgcn_mfma_f32_16x16x32_bf16(a0l, b1h, acc01, 0, 0, 0);
            acc10 = __builtin_amdgcn_mfma_f32_16x16x32_bf16(a1l, b0h, acc10, 0, 0, 0);
            acc11 = __builtin_amdgcn_mfma_f32_16x16x32_bf16(a1l, b1h, acc11, 0, 0, 0);
        }

        #pragma unroll
        for (int rt = 0; rt < 2; ++rt) {
            #pragma unroll
            for (int ct = 0; ct < 2; ++ct) {
                f32x4 a = rt ? (ct ? acc11 : acc10) : (ct ? acc01 : acc00);
                int col = nb + ct * 16 + li;
                #pragma unroll
                for (int j = 0; j < 4; ++j) {
                    int row = mb + rt * 16 + g * 4 + j;
                    if (row >= M) continue;
                    C[(size_t)row * 256 + col] = a[j];
                }
            }
        }
    }
}

// ---------------------------------------------------------------------------
// Scoring: 8 chunks x 32 cols, chunk = bid&7 -> XCD-local stripes. [verified]
// ---------------------------------------------------------------------------
__global__ __launch_bounds__(256) void k_score_part(
    const int* __restrict__ cand, const float* __restrict__ P,
    const float* __restrict__ Q, const float* __restrict__ b1,
    const float* __restrict__ W2, float* __restrict__ part)
{
    int bid = blockIdx.x;
    int c   = bid & 7;
    int grp = bid >> 3;
    int cd  = grp * 256 + threadIdx.x;
    if (cd >= N_CAND) return;

    int u = cand[2 * cd];
    int v = cand[2 * cd + 1];
    const float4* P4 = (const float4*)P;
    const float4* Q4 = (const float4*)Q;
    const float4* B4 = (const float4*)b1;
    const float4* W4 = (const float4*)W2;
    size_t pb = (size_t)u * 64 + c * 8;
    size_t qb = (size_t)v * 64 + c * 8;

    float4 p[8], q[8];
    #pragma unroll
    for (int i = 0; i < 8; ++i) p[i] = P4[pb + i];
    #pragma unroll
    for (int i = 0; i < 8; ++i) q[i] = Q4[qb + i];

    float acc = 0.f;
    #pragma unroll
    for (int i = 0; i < 8; ++i) {
        float4 b = B4[c * 8 + i];
        float4 w = W4[c * 8 + i];
        acc = fmaf(relu_f(p[i].x + q[i].x + b.x), w.x, acc);
        acc = fmaf(relu_f(p[i].y + q[i].y + b.y), w.y, acc);
        acc = fmaf(relu_f(p[i].z + q[i].z + b.z), w.z, acc);
        acc = fmaf(relu_f(p[i].w + q[i].w + b.w), w.w, acc);
    }
    part[(size_t)c * N_CAND + cd] = acc;
}

__global__ void k_sred(const float* __restrict__ part,
                       const float* __restrict__ b2, float* __restrict__ out)
{
    int i = blockIdx.x * 256 + threadIdx.x;
    if (i >= N_CAND) return;
    float s = b2[0];
    #pragma unroll
    for (int c = 0; c < 8; ++c) s += part[(size_t)c * N_CAND + i];
    out[i] = s;
}

// ---------------------------------------------------------------------------
extern "C" void kernel_launch(void* const* d_in, const int* in_sizes, int n_in,
                              void* d_out, int out_size, void* d_ws, size_t ws_size,
                              hipStream_t stream)
{
    const int*   atom_types = (const int*)d_in[0];
    const int*   edge_index = (const int*)d_in[2];
    const int*   candidates = (const int*)d_in[3];
    const float* atom_embed = (const float*)d_in[4];
    const float* atom_W     = (const float*)d_in[5];
    const float* atom_b     = (const float*)d_in[6];
    const float* conv_W     = (const float*)d_in[10];
    const float* conv_b     = (const float*)d_in[11];
    const float* s_W1       = (const float*)d_in[12];
    const float* s_b1       = (const float*)d_in[13];
    const float* s_W2       = (const float*)d_in[14];
    const float* s_b2       = (const float*)d_in[15];
    float* out = (float*)d_out;

    char* w = (char*)d_ws;
    size_t o = 0;
    auto alloc = [&](size_t bytes) {
        void* p = w + o;
        o += (bytes + 255) & ~(size_t)255;
        return p;
    };
    int*            ints = (int*)alloc((size_t)3 * N_NODES * 4);
    float*          h0   = (float*)alloc((size_t)N_NODES * HID * 4);
    float*          h1   = (float*)alloc((size_t)N_NODES * HID * 4);
    float*          Pm   = (float*)alloc((size_t)N_NODES * HID * 4);
    float*          Qm   = (float*)alloc((size_t)N_NODES * HID * 4);
    unsigned short* Ah   = (unsigned short*)alloc((size_t)N_NODES * HID * 2);
    unsigned short* Al   = (unsigned short*)alloc((size_t)N_NODES * HID * 2);
    unsigned short* WTh  = (unsigned short*)alloc((size_t)5 * 65536 * 2);
    unsigned short* WTl  = (unsigned short*)alloc((size_t)5 * 65536 * 2);
    float*          E0   = (float*)alloc((size_t)N_ATYPE * HID * 4);
    float*          part = (float*)alloc((size_t)8 * N_CAND * 4);
    float*          ns   = (float*)alloc((size_t)N_NODES * 4);
    float*          nd   = (float*)alloc((size_t)N_NODES * 4);
    int*            off  = (int*)alloc((size_t)(N_NODES + 1) * 4);
    int*            csr  = (int*)alloc((size_t)N_EDGES * 4);
    int* dego = ints;
    int* degi = ints + N_NODES;
    int* cur  = ints + 2 * N_NODES;

    hipMemsetAsync(ints, 0, (size_t)3 * N_NODES * 4, stream);

    k_prep<<<1280, 256, 0, stream>>>(conv_W, s_W1, atom_embed, atom_W, atom_b,
                                     edge_index, WTh, WTl, E0, dego, degi);
    k_nhs<<<2501, 256, 0, stream>>>(atom_types, E0, dego, degi, ns, nd, h0, off);
    k_fill<<<(N_EDGES + 255) / 256, 256, 0, stream>>>(edge_index, off, cur, csr);

    const float* hc = h0;
    float* hn = h1;
    for (int L = 0; L < 2; ++L) {
        k_agg<<<2048, 256, 0, stream>>>(hc, nd, off, csr, Ah, Al);
        k_conv<<<628, 256, 0, stream>>>(
            Ah, Al, WTh + (size_t)L * 65536, WTl + (size_t)L * 65536,
            conv_b + (size_t)L * HID, ns, hn, N_NODES);
        float* t = (float*)hc; hc = hn; hn = t;
    }
    // layer 2: agg then fused conv2+pq (626 blocks x 512 thr; P/Q split)
    k_agg<<<2048, 256, 0, stream>>>(hc, nd, off, csr, Ah, Al);
    k_convpq<<<626, 512, 0, stream>>>(
        Ah, Al, WTh + (size_t)2 * 65536, WTl + (size_t)2 * 65536,
        conv_b + (size_t)2 * HID, WTh, WTl, Pm, Qm, N_NODES);

    k_score_part<<<3128, 256, 0, stream>>>(candidates, Pm, Qm, s_b1, s_W2, part);
    k_sred<<<(N_CAND + 255) / 256, 256, 0, stream>>>(part, s_b2, out);
}

// Round 21
// 337.314 us; speedup vs baseline: 1.0175x; 1.0175x over previous
//
#include <hip/hip_runtime.h>

#define N_NODES 10000
#define N_EDGES 320000
#define N_CAND  100000
#define HID     256
#define N_MP    3
#define N_ATYPE 100

typedef short bf16x8 __attribute__((ext_vector_type(8)));
typedef float f32x4  __attribute__((ext_vector_type(4)));

static __device__ __forceinline__ float relu_f(float x) { return x > 0.f ? x : 0.f; }

// split fp32 -> bf16 hi (truncate) + bf16 lo (RNE of residual)
static __device__ __forceinline__ void split_bf16(float s, unsigned short& hi,
                                                  unsigned short& lo)
{
    unsigned u = __float_as_uint(s);
    hi = (unsigned short)(u >> 16);
    float rem = s - __uint_as_float(u & 0xffff0000u);
    unsigned v = __float_as_uint(rem);
    unsigned r = v + 0x7fffu + ((v >> 16) & 1u);
    lo = (unsigned short)(r >> 16);
}

// LDS 16B-block swizzle: consistent on write and read (verified R19)
static __device__ __forceinline__ int swz_blk(int rloc, int blk)
{
    return blk ^ (rloc & 7) ^ ((rloc & 3) << 3);
}

// ---------------------------------------------------------------------------
// bf16x3 MFMA 32x32 tile (verified R10-R20: absmax 3.8e-6).
// ---------------------------------------------------------------------------
static __device__ __forceinline__ void mfma_tile(
    const unsigned short* __restrict__ Ah, const unsigned short* __restrict__ Al,
    const unsigned short* __restrict__ Wh, const unsigned short* __restrict__ Wl,
    const float* __restrict__ bias, const float* __restrict__ scale,
    float* __restrict__ outF, int M, int mb, int nb, int doRelu)
{
    int l  = threadIdx.x & 63;
    int li = l & 15;
    int g  = l >> 4;

    int r0 = mb + li;       if (r0 >= M) r0 = M - 1;
    int r1 = mb + 16 + li;  if (r1 >= M) r1 = M - 1;
    int c0 = nb + li;
    int c1 = nb + 16 + li;

    const unsigned short* pA0h = Ah + (size_t)r0 * 256 + g * 8;
    const unsigned short* pA1h = Ah + (size_t)r1 * 256 + g * 8;
    const unsigned short* pA0l = Al + (size_t)r0 * 256 + g * 8;
    const unsigned short* pA1l = Al + (size_t)r1 * 256 + g * 8;
    const unsigned short* pB0h = Wh + (size_t)c0 * 256 + g * 8;
    const unsigned short* pB1h = Wh + (size_t)c1 * 256 + g * 8;
    const unsigned short* pB0l = Wl + (size_t)c0 * 256 + g * 8;
    const unsigned short* pB1l = Wl + (size_t)c1 * 256 + g * 8;

    f32x4 acc00 = {0.f, 0.f, 0.f, 0.f};
    f32x4 acc01 = {0.f, 0.f, 0.f, 0.f};
    f32x4 acc10 = {0.f, 0.f, 0.f, 0.f};
    f32x4 acc11 = {0.f, 0.f, 0.f, 0.f};

    #pragma unroll
    for (int ks = 0; ks < 8; ++ks) {
        int o = ks * 32;
        bf16x8 a0h = *(const bf16x8*)(pA0h + o);
        bf16x8 a1h = *(const bf16x8*)(pA1h + o);
        bf16x8 a0l = *(const bf16x8*)(pA0l + o);
        bf16x8 a1l = *(const bf16x8*)(pA1l + o);
        bf16x8 b0h = *(const bf16x8*)(pB0h + o);
        bf16x8 b1h = *(const bf16x8*)(pB1h + o);
        bf16x8 b0l = *(const bf16x8*)(pB0l + o);
        bf16x8 b1l = *(const bf16x8*)(pB1l + o);

        acc00 = __builtin_amdgcn_mfma_f32_16x16x32_bf16(a0h, b0h, acc00, 0, 0, 0);
        acc01 = __builtin_amdgcn_mfma_f32_16x16x32_bf16(a0h, b1h, acc01, 0, 0, 0);
        acc10 = __builtin_amdgcn_mfma_f32_16x16x32_bf16(a1h, b0h, acc10, 0, 0, 0);
        acc11 = __builtin_amdgcn_mfma_f32_16x16x32_bf16(a1h, b1h, acc11, 0, 0, 0);

        acc00 = __builtin_amdgcn_mfma_f32_16x16x32_bf16(a0h, b0l, acc00, 0, 0, 0);
        acc01 = __builtin_amdgcn_mfma_f32_16x16x32_bf16(a0h, b1l, acc01, 0, 0, 0);
        acc10 = __builtin_amdgcn_mfma_f32_16x16x32_bf16(a1h, b0l, acc10, 0, 0, 0);
        acc11 = __builtin_amdgcn_mfma_f32_16x16x32_bf16(a1h, b1l, acc11, 0, 0, 0);

        acc00 = __builtin_amdgcn_mfma_f32_16x16x32_bf16(a0l, b0h, acc00, 0, 0, 0);
        acc01 = __builtin_amdgcn_mfma_f32_16x16x32_bf16(a0l, b1h, acc01, 0, 0, 0);
        acc10 = __builtin_amdgcn_mfma_f32_16x16x32_bf16(a1l, b0h, acc10, 0, 0, 0);
        acc11 = __builtin_amdgcn_mfma_f32_16x16x32_bf16(a1l, b1h, acc11, 0, 0, 0);
    }

    #pragma unroll
    for (int rt = 0; rt < 2; ++rt) {
        #pragma unroll
        for (int ct = 0; ct < 2; ++ct) {
            f32x4 a = rt ? (ct ? acc11 : acc10) : (ct ? acc01 : acc00);
            int col = nb + ct * 16 + li;
            float bv = bias ? bias[col] : 0.f;
            #pragma unroll
            for (int j = 0; j < 4; ++j) {
                int row = mb + rt * 16 + g * 4 + j;
                if (row >= M) continue;
                float v = a[j] + bv;
                if (doRelu) v = relu_f(v);
                if (scale) v *= scale[row];
                outF[(size_t)row * 256 + col] = v;
            }
        }
    }
}

// ---------------------------------------------------------------------------
// E0 tile via direct fp32 operands (in-register split). [verified R17]
// ---------------------------------------------------------------------------
static __device__ __forceinline__ void mfma_tile_e0(
    const float* __restrict__ A, const float* __restrict__ B,
    const float* __restrict__ bias, float* __restrict__ C,
    int M, int mb, int nb)
{
    int l  = threadIdx.x & 63;
    int li = l & 15;
    int g  = l >> 4;

    int r0 = mb + li;       if (r0 >= M) r0 = M - 1;
    int r1 = mb + 16 + li;  if (r1 >= M) r1 = M - 1;
    int c0 = nb + li;
    int c1 = nb + 16 + li;

    f32x4 acc00 = {0.f, 0.f, 0.f, 0.f};
    f32x4 acc01 = {0.f, 0.f, 0.f, 0.f};
    f32x4 acc10 = {0.f, 0.f, 0.f, 0.f};
    f32x4 acc11 = {0.f, 0.f, 0.f, 0.f};

    #pragma unroll
    for (int ks = 0; ks < 8; ++ks) {
        int k0 = ks * 32 + g * 8;
        float av0[8], av1[8];
        {
            float4 x0 = *(const float4*)(A + (size_t)r0 * 256 + k0);
            float4 x1 = *(const float4*)(A + (size_t)r0 * 256 + k0 + 4);
            av0[0]=x0.x; av0[1]=x0.y; av0[2]=x0.z; av0[3]=x0.w;
            av0[4]=x1.x; av0[5]=x1.y; av0[6]=x1.z; av0[7]=x1.w;
            float4 y0 = *(const float4*)(A + (size_t)r1 * 256 + k0);
            float4 y1 = *(const float4*)(A + (size_t)r1 * 256 + k0 + 4);
            av1[0]=y0.x; av1[1]=y0.y; av1[2]=y0.z; av1[3]=y0.w;
            av1[4]=y1.x; av1[5]=y1.y; av1[6]=y1.z; av1[7]=y1.w;
        }
        float bv0[8], bv1[8];
        #pragma unroll
        for (int j = 0; j < 8; ++j) {
            bv0[j] = B[(size_t)(k0 + j) * 256 + c0];
            bv1[j] = B[(size_t)(k0 + j) * 256 + c1];
        }
        bf16x8 a0h, a0l, a1h, a1l, b0h, b0l, b1h, b1l;
        #pragma unroll
        for (int j = 0; j < 8; ++j) {
            unsigned short h, lo;
            split_bf16(av0[j], h, lo); a0h[j] = (short)h; a0l[j] = (short)lo;
            split_bf16(av1[j], h, lo); a1h[j] = (short)h; a1l[j] = (short)lo;
            split_bf16(bv0[j], h, lo); b0h[j] = (short)h; b0l[j] = (short)lo;
            split_bf16(bv1[j], h, lo); b1h[j] = (short)h; b1l[j] = (short)lo;
        }

        acc00 = __builtin_amdgcn_mfma_f32_16x16x32_bf16(a0h, b0h, acc00, 0, 0, 0);
        acc01 = __builtin_amdgcn_mfma_f32_16x16x32_bf16(a0h, b1h, acc01, 0, 0, 0);
        acc10 = __builtin_amdgcn_mfma_f32_16x16x32_bf16(a1h, b0h, acc10, 0, 0, 0);
        acc11 = __builtin_amdgcn_mfma_f32_16x16x32_bf16(a1h, b1h, acc11, 0, 0, 0);

        acc00 = __builtin_amdgcn_mfma_f32_16x16x32_bf16(a0h, b0l, acc00, 0, 0, 0);
        acc01 = __builtin_amdgcn_mfma_f32_16x16x32_bf16(a0h, b1l, acc01, 0, 0, 0);
        acc10 = __builtin_amdgcn_mfma_f32_16x16x32_bf16(a1h, b0l, acc10, 0, 0, 0);
        acc11 = __builtin_amdgcn_mfma_f32_16x16x32_bf16(a1h, b1l, acc11, 0, 0, 0);

        acc00 = __builtin_amdgcn_mfma_f32_16x16x32_bf16(a0l, b0h, acc00, 0, 0, 0);
        acc01 = __builtin_amdgcn_mfma_f32_16x16x32_bf16(a0l, b1h, acc01, 0, 0, 0);
        acc10 = __builtin_amdgcn_mfma_f32_16x16x32_bf16(a1l, b0h, acc10, 0, 0, 0);
        acc11 = __builtin_amdgcn_mfma_f32_16x16x32_bf16(a1l, b1h, acc11, 0, 0, 0);
    }

    #pragma unroll
    for (int rt = 0; rt < 2; ++rt) {
        #pragma unroll
        for (int ct = 0; ct < 2; ++ct) {
            f32x4 a = rt ? (ct ? acc11 : acc10) : (ct ? acc01 : acc00);
            int col = nb + ct * 16 + li;
            float bv = bias[col];
            #pragma unroll
            for (int j = 0; j < 4; ++j) {
                int row = mb + rt * 16 + g * 4 + j;
                if (row >= M) continue;
                C[(size_t)row * 256 + col] = a[j] + bv;
            }
        }
    }
}

// ---------------------------------------------------------------------------
// k_prep: LDS-transpose weight split (blocks 0..79) + E0 MFMA (blocks 80..87)
// + degree histogram (all blocks, strided). Grid: 1280 x 256. [verified R19]
// ---------------------------------------------------------------------------
__global__ __launch_bounds__(256) void k_prep(
    const float* __restrict__ conv_W, const float* __restrict__ s_W1,
    const float* __restrict__ atom_embed, const float* __restrict__ atom_W,
    const float* __restrict__ atom_b, const int* __restrict__ ei,
    unsigned short* __restrict__ WTh, unsigned short* __restrict__ WTl,
    float* __restrict__ E0, int* __restrict__ dout, int* __restrict__ din)
{
    int bid = blockIdx.x;
    if (bid < 80) {
        __shared__ float T[64][65];
        int mat = bid >> 4;
        int t   = bid & 15;
        int ti  = t >> 2;
        int tj  = t & 3;
        const float* src = (mat < 3) ? conv_W + (size_t)mat * 65536
                                     : s_W1 + (size_t)(mat - 3) * 65536;
        #pragma unroll
        for (int i = 0; i < 16; ++i) {
            int flat = i * 256 + threadIdx.x;
            int kr = flat >> 6;
            int nc = flat & 63;
            T[kr][nc] = src[(size_t)(ti * 64 + kr) * 256 + tj * 64 + nc];
        }
        __syncthreads();
        #pragma unroll
        for (int i = 0; i < 16; ++i) {
            int flat = i * 256 + threadIdx.x;
            int nr = flat >> 6;
            int kc = flat & 63;
            unsigned short hi, lo;
            split_bf16(T[kc][nr], hi, lo);
            size_t oi = (size_t)mat * 65536 +
                        (size_t)(tj * 64 + nr) * 256 + ti * 64 + kc;
            WTh[oi] = hi;
            WTl[oi] = lo;
        }
    } else if (bid < 88) {
        int w = (bid - 80) * 4 + (threadIdx.x >> 6);
        if (w < 32) {
            int x = w >> 3, y = w & 7;
            mfma_tile_e0(atom_embed, atom_W, atom_b, E0, N_ATYPE, x * 32, y * 32);
        }
    }
    int gidx = bid * 256 + threadIdx.x;
    if (gidx < N_EDGES) {
        atomicAdd(&dout[ei[gidx]], 1);
        atomicAdd(&din[ei[N_EDGES + gidx]], 1);
    }
}

// ---------------------------------------------------------------------------
// k_nhs: norm + h0 (blocks 0..2499) + degi exclusive scan (block 2500).
// ---------------------------------------------------------------------------
__global__ __launch_bounds__(256) void k_nhs(
    const int* __restrict__ types, const float* __restrict__ E0,
    const int* __restrict__ dout, const int* __restrict__ din,
    float* __restrict__ ns, float* __restrict__ nd, float* __restrict__ h,
    int* __restrict__ off)
{
    if (blockIdx.x == 2500) {
        __shared__ int part[256];
        int t = threadIdx.x;
        const int chunk = 40;
        int base = t * chunk;
        int s = 0;
        for (int i = 0; i < chunk; ++i) {
            int idx = base + i;
            if (idx < N_NODES) s += din[idx];
        }
        part[t] = s;
        __syncthreads();
        for (int d = 1; d < 256; d <<= 1) {
            int v = (t >= d) ? part[t - d] : 0;
            __syncthreads();
            part[t] += v;
            __syncthreads();
        }
        int run = (t == 0) ? 0 : part[t - 1];
        if (t == 0) off[0] = 0;
        for (int i = 0; i < chunk; ++i) {
            int idx = base + i;
            if (idx < N_NODES) { run += din[idx]; off[idx + 1] = run; }
        }
        return;
    }
    int node = blockIdx.x * 4 + (threadIdx.x >> 6);
    int lane = threadIdx.x & 63;
    if (node >= N_NODES) return;
    int o  = dout[node];
    int in = din[node];
    float nsv = (o  > 0) ? (1.0f / sqrtf((float)o))  : 0.f;
    float ndv = (in > 0) ? (1.0f / sqrtf((float)in)) : 0.f;
    if (lane == 0) { ns[node] = nsv; nd[node] = ndv; }
    int t = types[node];
    float4 v = ((const float4*)E0)[(size_t)t * 64 + lane];
    v.x *= nsv; v.y *= nsv; v.z *= nsv; v.w *= nsv;
    ((float4*)h)[(size_t)node * 64 + lane] = v;
}

__global__ void k_fill(const int* __restrict__ ei, const int* __restrict__ off,
                       int* __restrict__ cur, int* __restrict__ csr)
{
    int e = blockIdx.x * blockDim.x + threadIdx.x;
    if (e >= N_EDGES) return;
    int d = ei[N_EDGES + e];
    int p = off[d] + atomicAdd(&cur[d], 1);
    csr[p] = ei[e];
}

// ---------------------------------------------------------------------------
// Persistent column-chunked aggregation. [verified R10/R14]
// ---------------------------------------------------------------------------
__global__ __launch_bounds__(256) void k_agg(
    const float* __restrict__ h, const float* __restrict__ nd,
    const int* __restrict__ off, const int* __restrict__ csr,
    unsigned short* __restrict__ Ah, unsigned short* __restrict__ Al)
{
    int bid  = blockIdx.x;
    int slot = bid & 7;
    int c    = slot >> 1;
    int p    = ((bid >> 3) << 1) | (slot & 1);
    int wave = threadIdx.x >> 6;
    int lane = threadIdx.x & 63;
    int wi   = p * 4 + wave;
    int col  = c * 64 + lane;

    for (int node = wi; node < N_NODES; node += 2048) {
        int s0 = off[node], s1 = off[node + 1];
        float a0 = 0.f, a1 = 0.f, a2 = 0.f, a3 = 0.f;
        float a4 = 0.f, a5 = 0.f, a6 = 0.f, a7 = 0.f;
        int e = s0;
        for (; e + 8 <= s1; e += 8) {
            int i0 = csr[e],     i1 = csr[e + 1], i2 = csr[e + 2], i3 = csr[e + 3];
            int i4 = csr[e + 4], i5 = csr[e + 5], i6 = csr[e + 6], i7 = csr[e + 7];
            float v0 = h[(size_t)i0 * 256 + col];
            float v1 = h[(size_t)i1 * 256 + col];
            float v2 = h[(size_t)i2 * 256 + col];
            float v3 = h[(size_t)i3 * 256 + col];
            float v4 = h[(size_t)i4 * 256 + col];
            float v5 = h[(size_t)i5 * 256 + col];
            float v6 = h[(size_t)i6 * 256 + col];
            float v7 = h[(size_t)i7 * 256 + col];
            a0 += v0; a1 += v1; a2 += v2; a3 += v3;
            a4 += v4; a5 += v5; a6 += v6; a7 += v7;
        }
        for (; e < s1; ++e)
            a0 += h[(size_t)csr[e] * 256 + col];
        float s = (((a0 + a1) + (a2 + a3)) + ((a4 + a5) + (a6 + a7))) * nd[node];
        unsigned short hi, lo;
        split_bf16(s, hi, lo);
        Ah[(size_t)node * 256 + col] = hi;
        Al[(size_t)node * 256 + col] = lo;
    }
}

// conv GEMM (layers 0,1): fp32 out, relu, ns scale. 628 blocks x 256 thr.
__global__ __launch_bounds__(256) void k_conv(
    const unsigned short* __restrict__ Ah, const unsigned short* __restrict__ Al,
    const unsigned short* __restrict__ Wh, const unsigned short* __restrict__ Wl,
    const float* __restrict__ bias, const float* __restrict__ scale,
    float* __restrict__ outF, int M)
{
    int t = blockIdx.x * 4 + (threadIdx.x >> 6);
    int x = t >> 3, y = t & 7;
    if (x * 32 >= M) return;
    mfma_tile(Ah, Al, Wh, Wl, bias, scale, outF, M, x * 32, y * 32, 1);
}

// ---------------------------------------------------------------------------
// k_convpq v3: fused conv layer 2 + P/Q projection. Grid: 313 x 1024.
// Phase 1: waves 0..7 compute the 8 conv tiles of the 32-row panel -> LDS
//   (swizzled split-bf16). Waves 8..15 wait at the barrier (no extra work,
//   no extra fetch — R20's duplicate-phase-1 regressed on both).
// Phase 2: SIXTEEN P/Q tiles, ONE per wave (R19 did 2 serial per wave).
// Critical path 3 tiles -> 2; waves/CU 9.8 -> 19.6.
// ---------------------------------------------------------------------------
__global__ __launch_bounds__(1024) void k_convpq(
    const unsigned short* __restrict__ Ah, const unsigned short* __restrict__ Al,
    const unsigned short* __restrict__ Wch, const unsigned short* __restrict__ Wcl,
    const float* __restrict__ bias,
    const unsigned short* __restrict__ WTh, const unsigned short* __restrict__ WTl,
    float* __restrict__ P, float* __restrict__ Q, int M)
{
    __shared__ unsigned short Lh[32 * 256];
    __shared__ unsigned short Ll[32 * 256];

    int w  = threadIdx.x >> 6;           // 0..15
    int l  = threadIdx.x & 63;
    int li = l & 15;
    int g  = l >> 4;
    int mb = blockIdx.x * 32;

    if (mb + 32 > M) {
        for (int f = threadIdx.x; f < 32 * 256; f += 1024) {
            int r = f >> 8;
            if (mb + r >= M) { Lh[f] = 0; Ll[f] = 0; }
        }
    }

    // ---- phase 1: waves 0..7 compute conv tiles -> LDS ----
    if (w < 8) {
        int nb = w * 32;
        int r0 = mb + li;       if (r0 >= M) r0 = M - 1;
        int r1 = mb + 16 + li;  if (r1 >= M) r1 = M - 1;
        int c0 = nb + li;
        int c1 = nb + 16 + li;

        const unsigned short* pA0h = Ah + (size_t)r0 * 256 + g * 8;
        const unsigned short* pA1h = Ah + (size_t)r1 * 256 + g * 8;
        const unsigned short* pA0l = Al + (size_t)r0 * 256 + g * 8;
        const unsigned short* pA1l = Al + (size_t)r1 * 256 + g * 8;
        const unsigned short* pB0h = Wch + (size_t)c0 * 256 + g * 8;
        const unsigned short* pB1h = Wch + (size_t)c1 * 256 + g * 8;
        const unsigned short* pB0l = Wcl + (size_t)c0 * 256 + g * 8;
        const unsigned short* pB1l = Wcl + (size_t)c1 * 256 + g * 8;

        f32x4 acc00 = {0.f, 0.f, 0.f, 0.f};
        f32x4 acc01 = {0.f, 0.f, 0.f, 0.f};
        f32x4 acc10 = {0.f, 0.f, 0.f, 0.f};
        f32x4 acc11 = {0.f, 0.f, 0.f, 0.f};

        #pragma unroll
        for (int ks = 0; ks < 8; ++ks) {
            int o = ks * 32;
            bf16x8 a0h = *(const bf16x8*)(pA0h + o);
            bf16x8 a1h = *(const bf16x8*)(pA1h + o);
            bf16x8 a0l = *(const bf16x8*)(pA0l + o);
            bf16x8 a1l = *(const bf16x8*)(pA1l + o);
            bf16x8 b0h = *(const bf16x8*)(pB0h + o);
            bf16x8 b1h = *(const bf16x8*)(pB1h + o);
            bf16x8 b0l = *(const bf16x8*)(pB0l + o);
            bf16x8 b1l = *(const bf16x8*)(pB1l + o);

            acc00 = __builtin_amdgcn_mfma_f32_16x16x32_bf16(a0h, b0h, acc00, 0, 0, 0);
            acc01 = __builtin_amdgcn_mfma_f32_16x16x32_bf16(a0h, b1h, acc01, 0, 0, 0);
            acc10 = __builtin_amdgcn_mfma_f32_16x16x32_bf16(a1h, b0h, acc10, 0, 0, 0);
            acc11 = __builtin_amdgcn_mfma_f32_16x16x32_bf16(a1h, b1h, acc11, 0, 0, 0);

            acc00 = __builtin_amdgcn_mfma_f32_16x16x32_bf16(a0h, b0l, acc00, 0, 0, 0);
            acc01 = __builtin_amdgcn_mfma_f32_16x16x32_bf16(a0h, b1l, acc01, 0, 0, 0);
            acc10 = __builtin_amdgcn_mfma_f32_16x16x32_bf16(a1h, b0l, acc10, 0, 0, 0);
            acc11 = __builtin_amdgcn_mfma_f32_16x16x32_bf16(a1h, b1l, acc11, 0, 0, 0);

            acc00 = __builtin_amdgcn_mfma_f32_16x16x32_bf16(a0l, b0h, acc00, 0, 0, 0);
            acc01 = __builtin_amdgcn_mfma_f32_16x16x32_bf16(a0l, b1h, acc01, 0, 0, 0);
            acc10 = __builtin_amdgcn_mfma_f32_16x16x32_bf16(a1l, b0h, acc10, 0, 0, 0);
            acc11 = __builtin_amdgcn_mfma_f32_16x16x32_bf16(a1l, b1h, acc11, 0, 0, 0);
        }

        #pragma unroll
        for (int rt = 0; rt < 2; ++rt) {
            #pragma unroll
            for (int ct = 0; ct < 2; ++ct) {
                f32x4 a = rt ? (ct ? acc11 : acc10) : (ct ? acc01 : acc00);
                int col = nb + ct * 16 + li;
                float bv = bias[col];
                #pragma unroll
                for (int j = 0; j < 4; ++j) {
                    int rloc = rt * 16 + g * 4 + j;
                    if (mb + rloc >= M) continue;
                    float v = relu_f(a[j] + bv);
                    unsigned short hi, lo;
                    split_bf16(v, hi, lo);
                    int blk2 = swz_blk(rloc, col >> 3);
                    int addr = rloc * 256 + blk2 * 8 + (col & 7);
                    Lh[addr] = hi;
                    Ll[addr] = lo;
                }
            }
        }
    }
    __syncthreads();

    // ---- phase 2: one P/Q tile per wave (16 tiles across 16 waves) ----
    {
        int half = w >> 3;
        int y    = w & 7;
        const unsigned short* Bh = WTh + (size_t)(3 + half) * 65536;
        const unsigned short* Bl = WTl + (size_t)(3 + half) * 65536;
        float* C = half ? Q : P;
        int nb = y * 32;
        int c0 = nb + li;
        int c1 = nb + 16 + li;

        f32x4 acc00 = {0.f, 0.f, 0.f, 0.f};
        f32x4 acc01 = {0.f, 0.f, 0.f, 0.f};
        f32x4 acc10 = {0.f, 0.f, 0.f, 0.f};
        f32x4 acc11 = {0.f, 0.f, 0.f, 0.f};

        #pragma unroll
        for (int ks = 0; ks < 8; ++ks) {
            int blk = ks * 4 + g;
            int b0 = swz_blk(li, blk);
            bf16x8 a0h = *(const bf16x8*)(&Lh[li * 256 + b0 * 8]);
            bf16x8 a0l = *(const bf16x8*)(&Ll[li * 256 + b0 * 8]);
            bf16x8 a1h = *(const bf16x8*)(&Lh[(16 + li) * 256 + b0 * 8]);
            bf16x8 a1l = *(const bf16x8*)(&Ll[(16 + li) * 256 + b0 * 8]);

            int o = ks * 32 + g * 8;
            bf16x8 b0h = *(const bf16x8*)(Bh + (size_t)c0 * 256 + o);
            bf16x8 b1h = *(const bf16x8*)(Bh + (size_t)c1 * 256 + o);
            bf16x8 b0l = *(const bf16x8*)(Bl + (size_t)c0 * 256 + o);
            bf16x8 b1l = *(const bf16x8*)(Bl + (size_t)c1 * 256 + o);

            acc00 = __builtin_amdgcn_mfma_f32_16x16x32_bf16(a0h, b0h, acc00, 0, 0, 0);
            acc01 = __builtin_amdgcn_mfma_f32_16x16x32_bf16(a0h, b1h, acc01, 0, 0, 0);
            acc10 = __builtin_amdgcn_mfma_f32_16x16x32_bf16(a1h, b0h, acc10, 0, 0, 0);
            acc11 = __builtin_amdgcn_mfma_f32_16x16x32_bf16(a1h, b1h, acc11, 0, 0, 0);

            acc00 = __builtin_amdgcn_mfma_f32_16x16x32_bf16(a0h, b0l, acc00, 0, 0, 0);
            acc01 = __builtin_amdgcn_mfma_f32_16x16x32_bf16(a0h, b1l, acc01, 0, 0, 0);
            acc10 = __builtin_amdgcn_mfma_f32_16x16x32_bf16(a1h, b0l, acc10, 0, 0, 0);
            acc11 = __builtin_amdgcn_mfma_f32_16x16x32_bf16(a1h, b1l, acc11, 0, 0, 0);

            acc00 = __builtin_amdgcn_mfma_f32_16x16x32_bf16(a0l, b0h, acc00, 0, 0, 0);
            acc01 = __builtin_amdgcn_mfma_f32_16x16x32_bf16(a0l, b1h, acc01, 0, 0, 0);
            acc10 = __builtin_amdgcn_mfma_f32_16x16x32_bf16(a1l, b0h, acc10, 0, 0, 0);
            acc11 = __builtin_amdgcn_mfma_f32_16x16x32_bf16(a1l, b1h, acc11, 0, 0, 0);
        }

        #pragma unroll
        for (int rt = 0; rt < 2; ++rt) {
            #pragma unroll
            for (int ct = 0; ct < 2; ++ct) {
                f32x4 a = rt ? (ct ? acc11 : acc10) : (ct ? acc01 : acc00);
                int col = nb + ct * 16 + li;
                #pragma unroll
                for (int j = 0; j < 4; ++j) {
                    int row = mb + rt * 16 + g * 4 + j;
                    if (row >= M) continue;
                    C[(size_t)row * 256 + col] = a[j];
                }
            }
        }
    }
}

// ---------------------------------------------------------------------------
// Scoring: 8 chunks x 32 cols, chunk = bid&7 -> XCD-local stripes. [verified]
// ---------------------------------------------------------------------------
__global__ __launch_bounds__(256) void k_score_part(
    const int* __restrict__ cand, const float* __restrict__ P,
    const float* __restrict__ Q, const float* __restrict__ b1,
    const float* __restrict__ W2, float* __restrict__ part)
{
    int bid = blockIdx.x;
    int c   = bid & 7;
    int grp = bid >> 3;
    int cd  = grp * 256 + threadIdx.x;
    if (cd >= N_CAND) return;

    int u = cand[2 * cd];
    int v = cand[2 * cd + 1];
    const float4* P4 = (const float4*)P;
    const float4* Q4 = (const float4*)Q;
    const float4* B4 = (const float4*)b1;
    const float4* W4 = (const float4*)W2;
    size_t pb = (size_t)u * 64 + c * 8;
    size_t qb = (size_t)v * 64 + c * 8;

    float4 p[8], q[8];
    #pragma unroll
    for (int i = 0; i < 8; ++i) p[i] = P4[pb + i];
    #pragma unroll
    for (int i = 0; i < 8; ++i) q[i] = Q4[qb + i];

    float acc = 0.f;
    #pragma unroll
    for (int i = 0; i < 8; ++i) {
        float4 b = B4[c * 8 + i];
        float4 w = W4[c * 8 + i];
        acc = fmaf(relu_f(p[i].x + q[i].x + b.x), w.x, acc);
        acc = fmaf(relu_f(p[i].y + q[i].y + b.y), w.y, acc);
        acc = fmaf(relu_f(p[i].z + q[i].z + b.z), w.z, acc);
        acc = fmaf(relu_f(p[i].w + q[i].w + b.w), w.w, acc);
    }
    part[(size_t)c * N_CAND + cd] = acc;
}

__global__ void k_sred(const float* __restrict__ part,
                       const float* __restrict__ b2, float* __restrict__ out)
{
    int i = blockIdx.x * 256 + threadIdx.x;
    if (i >= N_CAND) return;
    float s = b2[0];
    #pragma unroll
    for (int c = 0; c < 8; ++c) s += part[(size_t)c * N_CAND + i];
    out[i] = s;
}

// ---------------------------------------------------------------------------
extern "C" void kernel_launch(void* const* d_in, const int* in_sizes, int n_in,
                              void* d_out, int out_size, void* d_ws, size_t ws_size,
                              hipStream_t stream)
{
    const int*   atom_types = (const int*)d_in[0];
    const int*   edge_index = (const int*)d_in[2];
    const int*   candidates = (const int*)d_in[3];
    const float* atom_embed = (const float*)d_in[4];
    const float* atom_W     = (const float*)d_in[5];
    const float* atom_b     = (const float*)d_in[6];
    const float* conv_W     = (const float*)d_in[10];
    const float* conv_b     = (const float*)d_in[11];
    const float* s_W1       = (const float*)d_in[12];
    const float* s_b1       = (const float*)d_in[13];
    const float* s_W2       = (const float*)d_in[14];
    const float* s_b2       = (const float*)d_in[15];
    float* out = (float*)d_out;

    char* w = (char*)d_ws;
    size_t o = 0;
    auto alloc = [&](size_t bytes) {
        void* p = w + o;
        o += (bytes + 255) & ~(size_t)255;
        return p;
    };
    int*            ints = (int*)alloc((size_t)3 * N_NODES * 4);
    float*          h0   = (float*)alloc((size_t)N_NODES * HID * 4);
    float*          h1   = (float*)alloc((size_t)N_NODES * HID * 4);
    float*          Pm   = (float*)alloc((size_t)N_NODES * HID * 4);
    float*          Qm   = (float*)alloc((size_t)N_NODES * HID * 4);
    unsigned short* Ah   = (unsigned short*)alloc((size_t)N_NODES * HID * 2);
    unsigned short* Al   = (unsigned short*)alloc((size_t)N_NODES * HID * 2);
    unsigned short* WTh  = (unsigned short*)alloc((size_t)5 * 65536 * 2);
    unsigned short* WTl  = (unsigned short*)alloc((size_t)5 * 65536 * 2);
    float*          E0   = (float*)alloc((size_t)N_ATYPE * HID * 4);
    float*          part = (float*)alloc((size_t)8 * N_CAND * 4);
    float*          ns   = (float*)alloc((size_t)N_NODES * 4);
    float*          nd   = (float*)alloc((size_t)N_NODES * 4);
    int*            off  = (int*)alloc((size_t)(N_NODES + 1) * 4);
    int*            csr  = (int*)alloc((size_t)N_EDGES * 4);
    int* dego = ints;
    int* degi = ints + N_NODES;
    int* cur  = ints + 2 * N_NODES;

    hipMemsetAsync(ints, 0, (size_t)3 * N_NODES * 4, stream);

    k_prep<<<1280, 256, 0, stream>>>(conv_W, s_W1, atom_embed, atom_W, atom_b,
                                     edge_index, WTh, WTl, E0, dego, degi);
    k_nhs<<<2501, 256, 0, stream>>>(atom_types, E0, dego, degi, ns, nd, h0, off);
    k_fill<<<(N_EDGES + 255) / 256, 256, 0, stream>>>(edge_index, off, cur, csr);

    const float* hc = h0;
    float* hn = h1;
    for (int L = 0; L < 2; ++L) {
        k_agg<<<2048, 256, 0, stream>>>(hc, nd, off, csr, Ah, Al);
        k_conv<<<628, 256, 0, stream>>>(
            Ah, Al, WTh + (size_t)L * 65536, WTl + (size_t)L * 65536,
            conv_b + (size_t)L * HID, ns, hn, N_NODES);
        float* t = (float*)hc; hc = hn; hn = t;
    }
    // layer 2: agg then fused conv2+pq (313 blocks x 1024 thr)
    k_agg<<<2048, 256, 0, stream>>>(hc, nd, off, csr, Ah, Al);
    k_convpq<<<313, 1024, 0, stream>>>(
        Ah, Al, WTh + (size_t)2 * 65536, WTl + (size_t)2 * 65536,
        conv_b + (size_t)2 * HID, WTh, WTl, Pm, Qm, N_NODES);

    k_score_part<<<3128, 256, 0, stream>>>(candidates, Pm, Qm, s_b1, s_W2, part);
    k_sred<<<(N_CAND + 255) / 256, 256, 0, stream>>>(part, s_b2, out);
}

// Round 22
// 334.922 us; speedup vs baseline: 1.0248x; 1.0071x over previous
//
#include <hip/hip_runtime.h>

#define N_NODES 10000
#define N_EDGES 320000
#define N_CAND  100000
#define HID     256
#define N_MP    3
#define N_ATYPE 100

typedef short bf16x8 __attribute__((ext_vector_type(8)));
typedef float f32x4  __attribute__((ext_vector_type(4)));

static __device__ __forceinline__ float relu_f(float x) { return x > 0.f ? x : 0.f; }

// split fp32 -> bf16 hi (truncate) + bf16 lo (RNE of residual)
static __device__ __forceinline__ void split_bf16(float s, unsigned short& hi,
                                                  unsigned short& lo)
{
    unsigned u = __float_as_uint(s);
    hi = (unsigned short)(u >> 16);
    float rem = s - __uint_as_float(u & 0xffff0000u);
    unsigned v = __float_as_uint(rem);
    unsigned r = v + 0x7fffu + ((v >> 16) & 1u);
    lo = (unsigned short)(r >> 16);
}

// LDS 16B-block swizzle: consistent on write and read (verified R19)
static __device__ __forceinline__ int swz_blk(int rloc, int blk)
{
    return blk ^ (rloc & 7) ^ ((rloc & 3) << 3);
}

// ---------------------------------------------------------------------------
// bf16x3 MFMA 32x32 tile (verified R10-R21: absmax 3.8e-6).
// ---------------------------------------------------------------------------
static __device__ __forceinline__ void mfma_tile(
    const unsigned short* __restrict__ Ah, const unsigned short* __restrict__ Al,
    const unsigned short* __restrict__ Wh, const unsigned short* __restrict__ Wl,
    const float* __restrict__ bias, const float* __restrict__ scale,
    float* __restrict__ outF, int M, int mb, int nb, int doRelu)
{
    int l  = threadIdx.x & 63;
    int li = l & 15;
    int g  = l >> 4;

    int r0 = mb + li;       if (r0 >= M) r0 = M - 1;
    int r1 = mb + 16 + li;  if (r1 >= M) r1 = M - 1;
    int c0 = nb + li;
    int c1 = nb + 16 + li;

    const unsigned short* pA0h = Ah + (size_t)r0 * 256 + g * 8;
    const unsigned short* pA1h = Ah + (size_t)r1 * 256 + g * 8;
    const unsigned short* pA0l = Al + (size_t)r0 * 256 + g * 8;
    const unsigned short* pA1l = Al + (size_t)r1 * 256 + g * 8;
    const unsigned short* pB0h = Wh + (size_t)c0 * 256 + g * 8;
    const unsigned short* pB1h = Wh + (size_t)c1 * 256 + g * 8;
    const unsigned short* pB0l = Wl + (size_t)c0 * 256 + g * 8;
    const unsigned short* pB1l = Wl + (size_t)c1 * 256 + g * 8;

    f32x4 acc00 = {0.f, 0.f, 0.f, 0.f};
    f32x4 acc01 = {0.f, 0.f, 0.f, 0.f};
    f32x4 acc10 = {0.f, 0.f, 0.f, 0.f};
    f32x4 acc11 = {0.f, 0.f, 0.f, 0.f};

    #pragma unroll
    for (int ks = 0; ks < 8; ++ks) {
        int o = ks * 32;
        bf16x8 a0h = *(const bf16x8*)(pA0h + o);
        bf16x8 a1h = *(const bf16x8*)(pA1h + o);
        bf16x8 a0l = *(const bf16x8*)(pA0l + o);
        bf16x8 a1l = *(const bf16x8*)(pA1l + o);
        bf16x8 b0h = *(const bf16x8*)(pB0h + o);
        bf16x8 b1h = *(const bf16x8*)(pB1h + o);
        bf16x8 b0l = *(const bf16x8*)(pB0l + o);
        bf16x8 b1l = *(const bf16x8*)(pB1l + o);

        acc00 = __builtin_amdgcn_mfma_f32_16x16x32_bf16(a0h, b0h, acc00, 0, 0, 0);
        acc01 = __builtin_amdgcn_mfma_f32_16x16x32_bf16(a0h, b1h, acc01, 0, 0, 0);
        acc10 = __builtin_amdgcn_mfma_f32_16x16x32_bf16(a1h, b0h, acc10, 0, 0, 0);
        acc11 = __builtin_amdgcn_mfma_f32_16x16x32_bf16(a1h, b1h, acc11, 0, 0, 0);

        acc00 = __builtin_amdgcn_mfma_f32_16x16x32_bf16(a0h, b0l, acc00, 0, 0, 0);
        acc01 = __builtin_amdgcn_mfma_f32_16x16x32_bf16(a0h, b1l, acc01, 0, 0, 0);
        acc10 = __builtin_amdgcn_mfma_f32_16x16x32_bf16(a1h, b0l, acc10, 0, 0, 0);
        acc11 = __builtin_amdgcn_mfma_f32_16x16x32_bf16(a1h, b1l, acc11, 0, 0, 0);

        acc00 = __builtin_amdgcn_mfma_f32_16x16x32_bf16(a0l, b0h, acc00, 0, 0, 0);
        acc01 = __builtin_amdgcn_mfma_f32_16x16x32_bf16(a0l, b1h, acc01, 0, 0, 0);
        acc10 = __builtin_amdgcn_mfma_f32_16x16x32_bf16(a1l, b0h, acc10, 0, 0, 0);
        acc11 = __builtin_amdgcn_mfma_f32_16x16x32_bf16(a1l, b1h, acc11, 0, 0, 0);
    }

    #pragma unroll
    for (int rt = 0; rt < 2; ++rt) {
        #pragma unroll
        for (int ct = 0; ct < 2; ++ct) {
            f32x4 a = rt ? (ct ? acc11 : acc10) : (ct ? acc01 : acc00);
            int col = nb + ct * 16 + li;
            float bv = bias ? bias[col] : 0.f;
            #pragma unroll
            for (int j = 0; j < 4; ++j) {
                int row = mb + rt * 16 + g * 4 + j;
                if (row >= M) continue;
                float v = a[j] + bv;
                if (doRelu) v = relu_f(v);
                if (scale) v *= scale[row];
                outF[(size_t)row * 256 + col] = v;
            }
        }
    }
}

// ---------------------------------------------------------------------------
// E0 tile via direct fp32 operands (in-register split). [verified R17]
// ---------------------------------------------------------------------------
static __device__ __forceinline__ void mfma_tile_e0(
    const float* __restrict__ A, const float* __restrict__ B,
    const float* __restrict__ bias, float* __restrict__ C,
    int M, int mb, int nb)
{
    int l  = threadIdx.x & 63;
    int li = l & 15;
    int g  = l >> 4;

    int r0 = mb + li;       if (r0 >= M) r0 = M - 1;
    int r1 = mb + 16 + li;  if (r1 >= M) r1 = M - 1;
    int c0 = nb + li;
    int c1 = nb + 16 + li;

    f32x4 acc00 = {0.f, 0.f, 0.f, 0.f};
    f32x4 acc01 = {0.f, 0.f, 0.f, 0.f};
    f32x4 acc10 = {0.f, 0.f, 0.f, 0.f};
    f32x4 acc11 = {0.f, 0.f, 0.f, 0.f};

    #pragma unroll
    for (int ks = 0; ks < 8; ++ks) {
        int k0 = ks * 32 + g * 8;
        float av0[8], av1[8];
        {
            float4 x0 = *(const float4*)(A + (size_t)r0 * 256 + k0);
            float4 x1 = *(const float4*)(A + (size_t)r0 * 256 + k0 + 4);
            av0[0]=x0.x; av0[1]=x0.y; av0[2]=x0.z; av0[3]=x0.w;
            av0[4]=x1.x; av0[5]=x1.y; av0[6]=x1.z; av0[7]=x1.w;
            float4 y0 = *(const float4*)(A + (size_t)r1 * 256 + k0);
            float4 y1 = *(const float4*)(A + (size_t)r1 * 256 + k0 + 4);
            av1[0]=y0.x; av1[1]=y0.y; av1[2]=y0.z; av1[3]=y0.w;
            av1[4]=y1.x; av1[5]=y1.y; av1[6]=y1.z; av1[7]=y1.w;
        }
        float bv0[8], bv1[8];
        #pragma unroll
        for (int j = 0; j < 8; ++j) {
            bv0[j] = B[(size_t)(k0 + j) * 256 + c0];
            bv1[j] = B[(size_t)(k0 + j) * 256 + c1];
        }
        bf16x8 a0h, a0l, a1h, a1l, b0h, b0l, b1h, b1l;
        #pragma unroll
        for (int j = 0; j < 8; ++j) {
            unsigned short h, lo;
            split_bf16(av0[j], h, lo); a0h[j] = (short)h; a0l[j] = (short)lo;
            split_bf16(av1[j], h, lo); a1h[j] = (short)h; a1l[j] = (short)lo;
            split_bf16(bv0[j], h, lo); b0h[j] = (short)h; b0l[j] = (short)lo;
            split_bf16(bv1[j], h, lo); b1h[j] = (short)h; b1l[j] = (short)lo;
        }

        acc00 = __builtin_amdgcn_mfma_f32_16x16x32_bf16(a0h, b0h, acc00, 0, 0, 0);
        acc01 = __builtin_amdgcn_mfma_f32_16x16x32_bf16(a0h, b1h, acc01, 0, 0, 0);
        acc10 = __builtin_amdgcn_mfma_f32_16x16x32_bf16(a1h, b0h, acc10, 0, 0, 0);
        acc11 = __builtin_amdgcn_mfma_f32_16x16x32_bf16(a1h, b1h, acc11, 0, 0, 0);

        acc00 = __builtin_amdgcn_mfma_f32_16x16x32_bf16(a0h, b0l, acc00, 0, 0, 0);
        acc01 = __builtin_amdgcn_mfma_f32_16x16x32_bf16(a0h, b1l, acc01, 0, 0, 0);
        acc10 = __builtin_amdgcn_mfma_f32_16x16x32_bf16(a1h, b0l, acc10, 0, 0, 0);
        acc11 = __builtin_amdgcn_mfma_f32_16x16x32_bf16(a1h, b1l, acc11, 0, 0, 0);

        acc00 = __builtin_amdgcn_mfma_f32_16x16x32_bf16(a0l, b0h, acc00, 0, 0, 0);
        acc01 = __builtin_amdgcn_mfma_f32_16x16x32_bf16(a0l, b1h, acc01, 0, 0, 0);
        acc10 = __builtin_amdgcn_mfma_f32_16x16x32_bf16(a1l, b0h, acc10, 0, 0, 0);
        acc11 = __builtin_amdgcn_mfma_f32_16x16x32_bf16(a1l, b1h, acc11, 0, 0, 0);
    }

    #pragma unroll
    for (int rt = 0; rt < 2; ++rt) {
        #pragma unroll
        for (int ct = 0; ct < 2; ++ct) {
            f32x4 a = rt ? (ct ? acc11 : acc10) : (ct ? acc01 : acc00);
            int col = nb + ct * 16 + li;
            float bv = bias[col];
            #pragma unroll
            for (int j = 0; j < 4; ++j) {
                int row = mb + rt * 16 + g * 4 + j;
                if (row >= M) continue;
                C[(size_t)row * 256 + col] = a[j] + bv;
            }
        }
    }
}

// ---------------------------------------------------------------------------
// k_prep: LDS-transpose weight split (blocks 0..79) + E0 MFMA (blocks 80..87)
// + degree histogram (all blocks, strided). Grid: 1280 x 256. [verified R19]
// ---------------------------------------------------------------------------
__global__ __launch_bounds__(256) void k_prep(
    const float* __restrict__ conv_W, const float* __restrict__ s_W1,
    const float* __restrict__ atom_embed, const float* __restrict__ atom_W,
    const float* __restrict__ atom_b, const int* __restrict__ ei,
    unsigned short* __restrict__ WTh, unsigned short* __restrict__ WTl,
    float* __restrict__ E0, int* __restrict__ dout, int* __restrict__ din)
{
    int bid = blockIdx.x;
    if (bid < 80) {
        __shared__ float T[64][65];
        int mat = bid >> 4;
        int t   = bid & 15;
        int ti  = t >> 2;
        int tj  = t & 3;
        const float* src = (mat < 3) ? conv_W + (size_t)mat * 65536
                                     : s_W1 + (size_t)(mat - 3) * 65536;
        #pragma unroll
        for (int i = 0; i < 16; ++i) {
            int flat = i * 256 + threadIdx.x;
            int kr = flat >> 6;
            int nc = flat & 63;
            T[kr][nc] = src[(size_t)(ti * 64 + kr) * 256 + tj * 64 + nc];
        }
        __syncthreads();
        #pragma unroll
        for (int i = 0; i < 16; ++i) {
            int flat = i * 256 + threadIdx.x;
            int nr = flat >> 6;
            int kc = flat & 63;
            unsigned short hi, lo;
            split_bf16(T[kc][nr], hi, lo);
            size_t oi = (size_t)mat * 65536 +
                        (size_t)(tj * 64 + nr) * 256 + ti * 64 + kc;
            WTh[oi] = hi;
            WTl[oi] = lo;
        }
    } else if (bid < 88) {
        int w = (bid - 80) * 4 + (threadIdx.x >> 6);
        if (w < 32) {
            int x = w >> 3, y = w & 7;
            mfma_tile_e0(atom_embed, atom_W, atom_b, E0, N_ATYPE, x * 32, y * 32);
        }
    }
    int gidx = bid * 256 + threadIdx.x;
    if (gidx < N_EDGES) {
        atomicAdd(&dout[ei[gidx]], 1);
        atomicAdd(&din[ei[N_EDGES + gidx]], 1);
    }
}

// ---------------------------------------------------------------------------
// k_nhs: norm + h0 (blocks 0..2499) + degi exclusive scan (block 2500).
// ---------------------------------------------------------------------------
__global__ __launch_bounds__(256) void k_nhs(
    const int* __restrict__ types, const float* __restrict__ E0,
    const int* __restrict__ dout, const int* __restrict__ din,
    float* __restrict__ ns, float* __restrict__ nd, float* __restrict__ h,
    int* __restrict__ off)
{
    if (blockIdx.x == 2500) {
        __shared__ int part[256];
        int t = threadIdx.x;
        const int chunk = 40;
        int base = t * chunk;
        int s = 0;
        for (int i = 0; i < chunk; ++i) {
            int idx = base + i;
            if (idx < N_NODES) s += din[idx];
        }
        part[t] = s;
        __syncthreads();
        for (int d = 1; d < 256; d <<= 1) {
            int v = (t >= d) ? part[t - d] : 0;
            __syncthreads();
            part[t] += v;
            __syncthreads();
        }
        int run = (t == 0) ? 0 : part[t - 1];
        if (t == 0) off[0] = 0;
        for (int i = 0; i < chunk; ++i) {
            int idx = base + i;
            if (idx < N_NODES) { run += din[idx]; off[idx + 1] = run; }
        }
        return;
    }
    int node = blockIdx.x * 4 + (threadIdx.x >> 6);
    int lane = threadIdx.x & 63;
    if (node >= N_NODES) return;
    int o  = dout[node];
    int in = din[node];
    float nsv = (o  > 0) ? (1.0f / sqrtf((float)o))  : 0.f;
    float ndv = (in > 0) ? (1.0f / sqrtf((float)in)) : 0.f;
    if (lane == 0) { ns[node] = nsv; nd[node] = ndv; }
    int t = types[node];
    float4 v = ((const float4*)E0)[(size_t)t * 64 + lane];
    v.x *= nsv; v.y *= nsv; v.z *= nsv; v.w *= nsv;
    ((float4*)h)[(size_t)node * 64 + lane] = v;
}

__global__ void k_fill(const int* __restrict__ ei, const int* __restrict__ off,
                       int* __restrict__ cur, int* __restrict__ csr)
{
    int e = blockIdx.x * blockDim.x + threadIdx.x;
    if (e >= N_EDGES) return;
    int d = ei[N_EDGES + e];
    int p = off[d] + atomicAdd(&cur[d], 1);
    csr[p] = ei[e];
}

// ---------------------------------------------------------------------------
// Persistent column-chunked aggregation. [verified R10/R14]
// ---------------------------------------------------------------------------
__global__ __launch_bounds__(256) void k_agg(
    const float* __restrict__ h, const float* __restrict__ nd,
    const int* __restrict__ off, const int* __restrict__ csr,
    unsigned short* __restrict__ Ah, unsigned short* __restrict__ Al)
{
    int bid  = blockIdx.x;
    int slot = bid & 7;
    int c    = slot >> 1;
    int p    = ((bid >> 3) << 1) | (slot & 1);
    int wave = threadIdx.x >> 6;
    int lane = threadIdx.x & 63;
    int wi   = p * 4 + wave;
    int col  = c * 64 + lane;

    for (int node = wi; node < N_NODES; node += 2048) {
        int s0 = off[node], s1 = off[node + 1];
        float a0 = 0.f, a1 = 0.f, a2 = 0.f, a3 = 0.f;
        float a4 = 0.f, a5 = 0.f, a6 = 0.f, a7 = 0.f;
        int e = s0;
        for (; e + 8 <= s1; e += 8) {
            int i0 = csr[e],     i1 = csr[e + 1], i2 = csr[e + 2], i3 = csr[e + 3];
            int i4 = csr[e + 4], i5 = csr[e + 5], i6 = csr[e + 6], i7 = csr[e + 7];
            float v0 = h[(size_t)i0 * 256 + col];
            float v1 = h[(size_t)i1 * 256 + col];
            float v2 = h[(size_t)i2 * 256 + col];
            float v3 = h[(size_t)i3 * 256 + col];
            float v4 = h[(size_t)i4 * 256 + col];
            float v5 = h[(size_t)i5 * 256 + col];
            float v6 = h[(size_t)i6 * 256 + col];
            float v7 = h[(size_t)i7 * 256 + col];
            a0 += v0; a1 += v1; a2 += v2; a3 += v3;
            a4 += v4; a5 += v5; a6 += v6; a7 += v7;
        }
        for (; e < s1; ++e)
            a0 += h[(size_t)csr[e] * 256 + col];
        float s = (((a0 + a1) + (a2 + a3)) + ((a4 + a5) + (a6 + a7))) * nd[node];
        unsigned short hi, lo;
        split_bf16(s, hi, lo);
        Ah[(size_t)node * 256 + col] = hi;
        Al[(size_t)node * 256 + col] = lo;
    }
}

// conv GEMM (layers 0,1): fp32 out, relu, ns scale. 628 blocks x 256 thr.
__global__ __launch_bounds__(256) void k_conv(
    const unsigned short* __restrict__ Ah, const unsigned short* __restrict__ Al,
    const unsigned short* __restrict__ Wh, const unsigned short* __restrict__ Wl,
    const float* __restrict__ bias, const float* __restrict__ scale,
    float* __restrict__ outF, int M)
{
    int t = blockIdx.x * 4 + (threadIdx.x >> 6);
    int x = t >> 3, y = t & 7;
    if (x * 32 >= M) return;
    mfma_tile(Ah, Al, Wh, Wl, bias, scale, outF, M, x * 32, y * 32, 1);
}

// ---------------------------------------------------------------------------
// k_convpq (R19 measured-best): fused conv layer 2 + P/Q projection.
// Grid 313 x 512. Phase 1: 8 waves, conv panel -> swizzled LDS. Phase 2:
// 16 P/Q tiles, 2 serial per wave. 62.5us measured; both occupancy variants
// (R20 dup-phase1 2x-blocks: 71.4; R21 16-wave: 64.7) regressed.
// ---------------------------------------------------------------------------
__global__ __launch_bounds__(512) void k_convpq(
    const unsigned short* __restrict__ Ah, const unsigned short* __restrict__ Al,
    const unsigned short* __restrict__ Wch, const unsigned short* __restrict__ Wcl,
    const float* __restrict__ bias,
    const unsigned short* __restrict__ WTh, const unsigned short* __restrict__ WTl,
    float* __restrict__ P, float* __restrict__ Q, int M)
{
    __shared__ unsigned short Lh[32 * 256];
    __shared__ unsigned short Ll[32 * 256];

    int w  = threadIdx.x >> 6;
    int l  = threadIdx.x & 63;
    int li = l & 15;
    int g  = l >> 4;
    int mb = blockIdx.x * 32;

    if (mb + 32 > M) {
        for (int f = threadIdx.x; f < 32 * 256; f += 512) {
            int r = f >> 8;
            if (mb + r >= M) { Lh[f] = 0; Ll[f] = 0; }
        }
    }

    // ---- phase 1: conv tile (mb, nb = w*32) -> LDS ----
    {
        int nb = w * 32;
        int r0 = mb + li;       if (r0 >= M) r0 = M - 1;
        int r1 = mb + 16 + li;  if (r1 >= M) r1 = M - 1;
        int c0 = nb + li;
        int c1 = nb + 16 + li;

        const unsigned short* pA0h = Ah + (size_t)r0 * 256 + g * 8;
        const unsigned short* pA1h = Ah + (size_t)r1 * 256 + g * 8;
        const unsigned short* pA0l = Al + (size_t)r0 * 256 + g * 8;
        const unsigned short* pA1l = Al + (size_t)r1 * 256 + g * 8;
        const unsigned short* pB0h = Wch + (size_t)c0 * 256 + g * 8;
        const unsigned short* pB1h = Wch + (size_t)c1 * 256 + g * 8;
        const unsigned short* pB0l = Wcl + (size_t)c0 * 256 + g * 8;
        const unsigned short* pB1l = Wcl + (size_t)c1 * 256 + g * 8;

        f32x4 acc00 = {0.f, 0.f, 0.f, 0.f};
        f32x4 acc01 = {0.f, 0.f, 0.f, 0.f};
        f32x4 acc10 = {0.f, 0.f, 0.f, 0.f};
        f32x4 acc11 = {0.f, 0.f, 0.f, 0.f};

        #pragma unroll
        for (int ks = 0; ks < 8; ++ks) {
            int o = ks * 32;
            bf16x8 a0h = *(const bf16x8*)(pA0h + o);
            bf16x8 a1h = *(const bf16x8*)(pA1h + o);
            bf16x8 a0l = *(const bf16x8*)(pA0l + o);
            bf16x8 a1l = *(const bf16x8*)(pA1l + o);
            bf16x8 b0h = *(const bf16x8*)(pB0h + o);
            bf16x8 b1h = *(const bf16x8*)(pB1h + o);
            bf16x8 b0l = *(const bf16x8*)(pB0l + o);
            bf16x8 b1l = *(const bf16x8*)(pB1l + o);

            acc00 = __builtin_amdgcn_mfma_f32_16x16x32_bf16(a0h, b0h, acc00, 0, 0, 0);
            acc01 = __builtin_amdgcn_mfma_f32_16x16x32_bf16(a0h, b1h, acc01, 0, 0, 0);
            acc10 = __builtin_amdgcn_mfma_f32_16x16x32_bf16(a1h, b0h, acc10, 0, 0, 0);
            acc11 = __builtin_amdgcn_mfma_f32_16x16x32_bf16(a1h, b1h, acc11, 0, 0, 0);

            acc00 = __builtin_amdgcn_mfma_f32_16x16x32_bf16(a0h, b0l, acc00, 0, 0, 0);
            acc01 = __builtin_amdgcn_mfma_f32_16x16x32_bf16(a0h, b1l, acc01, 0, 0, 0);
            acc10 = __builtin_amdgcn_mfma_f32_16x16x32_bf16(a1h, b0l, acc10, 0, 0, 0);
            acc11 = __builtin_amdgcn_mfma_f32_16x16x32_bf16(a1h, b1l, acc11, 0, 0, 0);

            acc00 = __builtin_amdgcn_mfma_f32_16x16x32_bf16(a0l, b0h, acc00, 0, 0, 0);
            acc01 = __builtin_amdgcn_mfma_f32_16x16x32_bf16(a0l, b1h, acc01, 0, 0, 0);
            acc10 = __builtin_amdgcn_mfma_f32_16x16x32_bf16(a1l, b0h, acc10, 0, 0, 0);
            acc11 = __builtin_amdgcn_mfma_f32_16x16x32_bf16(a1l, b1h, acc11, 0, 0, 0);
        }

        #pragma unroll
        for (int rt = 0; rt < 2; ++rt) {
            #pragma unroll
            for (int ct = 0; ct < 2; ++ct) {
                f32x4 a = rt ? (ct ? acc11 : acc10) : (ct ? acc01 : acc00);
                int col = nb + ct * 16 + li;
                float bv = bias[col];
                #pragma unroll
                for (int j = 0; j < 4; ++j) {
                    int rloc = rt * 16 + g * 4 + j;
                    if (mb + rloc >= M) continue;
                    float v = relu_f(a[j] + bv);
                    unsigned short hi, lo;
                    split_bf16(v, hi, lo);
                    int blk2 = swz_blk(rloc, col >> 3);
                    int addr = rloc * 256 + blk2 * 8 + (col & 7);
                    Lh[addr] = hi;
                    Ll[addr] = lo;
                }
            }
        }
    }
    __syncthreads();

    // ---- phase 2: two P/Q tiles per wave, A from LDS ----
    #pragma unroll
    for (int it = 0; it < 2; ++it) {
        int t = w + it * 8;              // 0..15
        int half = t >> 3;
        int y    = t & 7;
        const unsigned short* Bh = WTh + (size_t)(3 + half) * 65536;
        const unsigned short* Bl = WTl + (size_t)(3 + half) * 65536;
        float* C = half ? Q : P;
        int nb = y * 32;
        int c0 = nb + li;
        int c1 = nb + 16 + li;

        f32x4 acc00 = {0.f, 0.f, 0.f, 0.f};
        f32x4 acc01 = {0.f, 0.f, 0.f, 0.f};
        f32x4 acc10 = {0.f, 0.f, 0.f, 0.f};
        f32x4 acc11 = {0.f, 0.f, 0.f, 0.f};

        #pragma unroll
        for (int ks = 0; ks < 8; ++ks) {
            int blk = ks * 4 + g;
            int b0 = swz_blk(li, blk);
            bf16x8 a0h = *(const bf16x8*)(&Lh[li * 256 + b0 * 8]);
            bf16x8 a0l = *(const bf16x8*)(&Ll[li * 256 + b0 * 8]);
            bf16x8 a1h = *(const bf16x8*)(&Lh[(16 + li) * 256 + b0 * 8]);
            bf16x8 a1l = *(const bf16x8*)(&Ll[(16 + li) * 256 + b0 * 8]);

            int o = ks * 32 + g * 8;
            bf16x8 b0h = *(const bf16x8*)(Bh + (size_t)c0 * 256 + o);
            bf16x8 b1h = *(const bf16x8*)(Bh + (size_t)c1 * 256 + o);
            bf16x8 b0l = *(const bf16x8*)(Bl + (size_t)c0 * 256 + o);
            bf16x8 b1l = *(const bf16x8*)(Bl + (size_t)c1 * 256 + o);

            acc00 = __builtin_amdgcn_mfma_f32_16x16x32_bf16(a0h, b0h, acc00, 0, 0, 0);
            acc01 = __builtin_amdgcn_mfma_f32_16x16x32_bf16(a0h, b1h, acc01, 0, 0, 0);
            acc10 = __builtin_amdgcn_mfma_f32_16x16x32_bf16(a1h, b0h, acc10, 0, 0, 0);
            acc11 = __builtin_amdgcn_mfma_f32_16x16x32_bf16(a1h, b1h, acc11, 0, 0, 0);

            acc00 = __builtin_amdgcn_mfma_f32_16x16x32_bf16(a0h, b0l, acc00, 0, 0, 0);
            acc01 = __builtin_amdgcn_mfma_f32_16x16x32_bf16(a0h, b1l, acc01, 0, 0, 0);
            acc10 = __builtin_amdgcn_mfma_f32_16x16x32_bf16(a1h, b0l, acc10, 0, 0, 0);
            acc11 = __builtin_amdgcn_mfma_f32_16x16x32_bf16(a1h, b1l, acc11, 0, 0, 0);

            acc00 = __builtin_amdgcn_mfma_f32_16x16x32_bf16(a0l, b0h, acc00, 0, 0, 0);
            acc01 = __builtin_amdgcn_mfma_f32_16x16x32_bf16(a0l, b1h, acc01, 0, 0, 0);
            acc10 = __builtin_amdgcn_mfma_f32_16x16x32_bf16(a1l, b0h, acc10, 0, 0, 0);
            acc11 = __builtin_amdgcn_mfma_f32_16x16x32_bf16(a1l, b1h, acc11, 0, 0, 0);
        }

        #pragma unroll
        for (int rt = 0; rt < 2; ++rt) {
            #pragma unroll
            for (int ct = 0; ct < 2; ++ct) {
                f32x4 a = rt ? (ct ? acc11 : acc10) : (ct ? acc01 : acc00);
                int col = nb + ct * 16 + li;
                #pragma unroll
                for (int j = 0; j < 4; ++j) {
                    int row = mb + rt * 16 + g * 4 + j;
                    if (row >= M) continue;
                    C[(size_t)row * 256 + col] = a[j];
                }
            }
        }
    }
}

// ---------------------------------------------------------------------------
// Scoring: 8 chunks x 32 cols, chunk = bid&7 -> XCD-local stripes. [verified]
// ---------------------------------------------------------------------------
__global__ __launch_bounds__(256) void k_score_part(
    const int* __restrict__ cand, const float* __restrict__ P,
    const float* __restrict__ Q, const float* __restrict__ b1,
    const float* __restrict__ W2, float* __restrict__ part)
{
    int bid = blockIdx.x;
    int c   = bid & 7;
    int grp = bid >> 3;
    int cd  = grp * 256 + threadIdx.x;
    if (cd >= N_CAND) return;

    int u = cand[2 * cd];
    int v = cand[2 * cd + 1];
    const float4* P4 = (const float4*)P;
    const float4* Q4 = (const float4*)Q;
    const float4* B4 = (const float4*)b1;
    const float4* W4 = (const float4*)W2;
    size_t pb = (size_t)u * 64 + c * 8;
    size_t qb = (size_t)v * 64 + c * 8;

    float4 p[8], q[8];
    #pragma unroll
    for (int i = 0; i < 8; ++i) p[i] = P4[pb + i];
    #pragma unroll
    for (int i = 0; i < 8; ++i) q[i] = Q4[qb + i];

    float acc = 0.f;
    #pragma unroll
    for (int i = 0; i < 8; ++i) {
        float4 b = B4[c * 8 + i];
        float4 w = W4[c * 8 + i];
        acc = fmaf(relu_f(p[i].x + q[i].x + b.x), w.x, acc);
        acc = fmaf(relu_f(p[i].y + q[i].y + b.y), w.y, acc);
        acc = fmaf(relu_f(p[i].z + q[i].z + b.z), w.z, acc);
        acc = fmaf(relu_f(p[i].w + q[i].w + b.w), w.w, acc);
    }
    part[(size_t)c * N_CAND + cd] = acc;
}

__global__ void k_sred(const float* __restrict__ part,
                       const float* __restrict__ b2, float* __restrict__ out)
{
    int i = blockIdx.x * 256 + threadIdx.x;
    if (i >= N_CAND) return;
    float s = b2[0];
    #pragma unroll
    for (int c = 0; c < 8; ++c) s += part[(size_t)c * N_CAND + i];
    out[i] = s;
}

// ---------------------------------------------------------------------------
extern "C" void kernel_launch(void* const* d_in, const int* in_sizes, int n_in,
                              void* d_out, int out_size, void* d_ws, size_t ws_size,
                              hipStream_t stream)
{
    const int*   atom_types = (const int*)d_in[0];
    const int*   edge_index = (const int*)d_in[2];
    const int*   candidates = (const int*)d_in[3];
    const float* atom_embed = (const float*)d_in[4];
    const float* atom_W     = (const float*)d_in[5];
    const float* atom_b     = (const float*)d_in[6];
    const float* conv_W     = (const float*)d_in[10];
    const float* conv_b     = (const float*)d_in[11];
    const float* s_W1       = (const float*)d_in[12];
    const float* s_b1       = (const float*)d_in[13];
    const float* s_W2       = (const float*)d_in[14];
    const float* s_b2       = (const float*)d_in[15];
    float* out = (float*)d_out;

    char* w = (char*)d_ws;
    size_t o = 0;
    auto alloc = [&](size_t bytes) {
        void* p = w + o;
        o += (bytes + 255) & ~(size_t)255;
        return p;
    };
    int*            ints = (int*)alloc((size_t)3 * N_NODES * 4);
    float*          h0   = (float*)alloc((size_t)N_NODES * HID * 4);
    float*          h1   = (float*)alloc((size_t)N_NODES * HID * 4);
    float*          Pm   = (float*)alloc((size_t)N_NODES * HID * 4);
    float*          Qm   = (float*)alloc((size_t)N_NODES * HID * 4);
    unsigned short* Ah   = (unsigned short*)alloc((size_t)N_NODES * HID * 2);
    unsigned short* Al   = (unsigned short*)alloc((size_t)N_NODES * HID * 2);
    unsigned short* WTh  = (unsigned short*)alloc((size_t)5 * 65536 * 2);
    unsigned short* WTl  = (unsigned short*)alloc((size_t)5 * 65536 * 2);
    float*          E0   = (float*)alloc((size_t)N_ATYPE * HID * 4);
    float*          part = (float*)alloc((size_t)8 * N_CAND * 4);
    float*          ns   = (float*)alloc((size_t)N_NODES * 4);
    float*          nd   = (float*)alloc((size_t)N_NODES * 4);
    int*            off  = (int*)alloc((size_t)(N_NODES + 1) * 4);
    int*            csr  = (int*)alloc((size_t)N_EDGES * 4);
    int* dego = ints;
    int* degi = ints + N_NODES;
    int* cur  = ints + 2 * N_NODES;

    hipMemsetAsync(ints, 0, (size_t)3 * N_NODES * 4, stream);

    k_prep<<<1280, 256, 0, stream>>>(conv_W, s_W1, atom_embed, atom_W, atom_b,
                                     edge_index, WTh, WTl, E0, dego, degi);
    k_nhs<<<2501, 256, 0, stream>>>(atom_types, E0, dego, degi, ns, nd, h0, off);
    k_fill<<<(N_EDGES + 255) / 256, 256, 0, stream>>>(edge_index, off, cur, csr);

    const float* hc = h0;
    float* hn = h1;
    for (int L = 0; L < 2; ++L) {
        k_agg<<<2048, 256, 0, stream>>>(hc, nd, off, csr, Ah, Al);
        k_conv<<<628, 256, 0, stream>>>(
            Ah, Al, WTh + (size_t)L * 65536, WTl + (size_t)L * 65536,
            conv_b + (size_t)L * HID, ns, hn, N_NODES);
        float* t = (float*)hc; hc = hn; hn = t;
    }
    // layer 2: agg then fused conv2+pq (626... no: 313 blocks x 512 thr, R19)
    k_agg<<<2048, 256, 0, stream>>>(hc, nd, off, csr, Ah, Al);
    k_convpq<<<313, 512, 0, stream>>>(
        Ah, Al, WTh + (size_t)2 * 65536, WTl + (size_t)2 * 65536,
        conv_b + (size_t)2 * HID, WTh, WTl, Pm, Qm, N_NODES);

    k_score_part<<<3128, 256, 0, stream>>>(candidates, Pm, Qm, s_b1, s_W2, part);
    k_sred<<<(N_CAND + 255) / 256, 256, 0, stream>>>(part, s_b2, out);
}